// Round 5
// baseline (3398.549 us; speedup 1.0000x reference)
//
#include <hip/hip_runtime.h>
#include <hip/hip_bf16.h>

// Problem constants
#define BB   2
#define NN   50000
#define BN   100000     // B*N
#define NE   500000

#define EPITCH 136      // ein LDS pitch (bf16 elems): 64B-bank stride 4, 16B aligned
#define XPITCH 72       // node xs pitch
#define HPITCH 264      // hid LDS pitch

using u16 = unsigned short;
using u32 = unsigned int;
typedef __attribute__((ext_vector_type(8))) short short8;   // 8 x bf16 (4 VGPRs)
typedef __attribute__((ext_vector_type(4))) short short4v;  // 4 x bf16 (8B)
typedef __attribute__((ext_vector_type(4))) float f32x4;    // MFMA accumulator

__device__ __forceinline__ u16 f2bf(float f) {   // RNE f32 -> bf16 (finite inputs)
    union { float f; u32 u; } w; w.f = f;
    return (u16)((w.u + 0x7fffu + ((w.u >> 16) & 1u)) >> 16);
}

// ---------------------------------------------------------------------------
// Weight pre-swizzle: A-fragment layout for mfma_f32_16x16x32_bf16.
// frag element at [ntile][kblk][lane][j] = W^T[n][k] = W[k][n],
//   n = ntile*16 + (lane&15), k = kblk*32 + (lane>>4)*8 + j.
// Regions (u16 offsets): w1e @0 (16*4*64*8=32768), w1n @32768 (16*2*..=16384),
//                        w2e @49152 (8*8*..=32768), w2n @81920 (32768).
// ---------------------------------------------------------------------------
__global__ __launch_bounds__(256) void swizzle_weights(
    const float* __restrict__ ew1, const float* __restrict__ nw1,
    const float* __restrict__ ew2, const float* __restrict__ nw2,
    u16* __restrict__ frag)
{
    int idx = blockIdx.x * 256 + threadIdx.x;   // 0 .. 114687
    if (idx >= 114688) return;
    const float* src; int KB, NCOL, local;
    if (idx < 32768)      { local = idx;         src = ew1; KB = 4; NCOL = 256; }
    else if (idx < 49152) { local = idx - 32768; src = nw1; KB = 2; NCOL = 256; }
    else if (idx < 81920) { local = idx - 49152; src = ew2; KB = 8; NCOL = 128; }
    else                  { local = idx - 81920; src = nw2; KB = 8; NCOL = 128; }
    int j = local & 7, l = (local >> 3) & 63, rest = local >> 9;
    int kblk = rest % KB, ntile = rest / KB;
    int n = ntile * 16 + (l & 15);
    int k = kblk * 32 + ((l >> 4) << 3) + j;
    frag[idx] = f2bf(src[k * NCOL + n]);
}

// ---------------------------------------------------------------------------
// Node MLP: hbuf[r][:] = relu(x[r]@nw1+nb1)@nw2+nb2, 64 rows/block, MFMA.
// ---------------------------------------------------------------------------
__global__ __launch_bounds__(256) void node_mlp_kernel(
    const float* __restrict__ x, const float* __restrict__ nb1,
    const float* __restrict__ nb2, const u16* __restrict__ frag,
    float* __restrict__ hbuf)
{
    __shared__ u16 xs[64 * XPITCH];    // 9216 B
    __shared__ u16 hid[64 * HPITCH];   // 33792 B
    const int t = threadIdx.x;
    const int wave = t >> 6, l = t & 63, lane15 = l & 15, quad = l >> 4;
    const int r0 = blockIdx.x * 64;
    const int valid = min(64, BN - r0);

    // stage x tile (f32 -> bf16): 64 rows x 16 float4
    #pragma unroll
    for (int it = 0; it < 4; ++it) {
        int i = t + it * 256;
        int m = i >> 4, c4 = i & 15;
        int row = min(r0 + m, BN - 1);
        float4 g = ((const float4*)x)[(size_t)row * 16 + c4];
        short4v s;
        s.x = (short)f2bf(g.x); s.y = (short)f2bf(g.y);
        s.z = (short)f2bf(g.z); s.w = (short)f2bf(g.w);
        *(short4v*)(xs + m * XPITCH + c4 * 4) = s;
    }
    __syncthreads();

    // GEMM1^T: hid^T[n][m] = sum_k nw1^T[n][k] xs^T[k][m], K=64
    {
        f32x4 acc[4][4];
        #pragma unroll
        for (int i = 0; i < 4; ++i)
            #pragma unroll
            for (int mt = 0; mt < 4; ++mt) acc[i][mt] = f32x4{0.f,0.f,0.f,0.f};
        const u16* w1 = frag + 32768;    // [16][2][64][8]
        #pragma unroll
        for (int kblk = 0; kblk < 2; ++kblk) {
            short8 bf[4], af[4];
            #pragma unroll
            for (int mt = 0; mt < 4; ++mt)
                bf[mt] = *(const short8*)(xs + (mt*16 + lane15) * XPITCH + kblk*32 + quad*8);
            #pragma unroll
            for (int i = 0; i < 4; ++i)
                af[i] = *(const short8*)(w1 + (((wave*4 + i)*2 + kblk)*64 + l) * 8);
            #pragma unroll
            for (int i = 0; i < 4; ++i)
                #pragma unroll
                for (int mt = 0; mt < 4; ++mt)
                    acc[i][mt] = __builtin_amdgcn_mfma_f32_16x16x32_bf16(af[i], bf[mt], acc[i][mt], 0, 0, 0);
        }
        #pragma unroll
        for (int i = 0; i < 4; ++i) {
            int n0 = (wave*4 + i)*16 + quad*4;
            float4 bv = *(const float4*)(nb1 + n0);
            #pragma unroll
            for (int mt = 0; mt < 4; ++mt) {
                int m = mt*16 + lane15;
                short4v s;
                s.x = (short)f2bf(fmaxf(acc[i][mt][0] + bv.x, 0.f));
                s.y = (short)f2bf(fmaxf(acc[i][mt][1] + bv.y, 0.f));
                s.z = (short)f2bf(fmaxf(acc[i][mt][2] + bv.z, 0.f));
                s.w = (short)f2bf(fmaxf(acc[i][mt][3] + bv.w, 0.f));
                *(short4v*)(hid + m * HPITCH + n0) = s;
            }
        }
    }
    __syncthreads();

    // GEMM2^T: out^T[n2][m] = sum_k nw2^T[n2][k] hid^T[k][m], K=256 -> f32 store
    {
        f32x4 acc[2][4];
        #pragma unroll
        for (int i = 0; i < 2; ++i)
            #pragma unroll
            for (int mt = 0; mt < 4; ++mt) acc[i][mt] = f32x4{0.f,0.f,0.f,0.f};
        const u16* w2 = frag + 81920;    // [8][8][64][8]
        #pragma unroll
        for (int kblk = 0; kblk < 8; ++kblk) {
            short8 bf[4], af[2];
            #pragma unroll
            for (int mt = 0; mt < 4; ++mt)
                bf[mt] = *(const short8*)(hid + (mt*16 + lane15) * HPITCH + kblk*32 + quad*8);
            #pragma unroll
            for (int i = 0; i < 2; ++i)
                af[i] = *(const short8*)(w2 + (((wave*2 + i)*8 + kblk)*64 + l) * 8);
            #pragma unroll
            for (int i = 0; i < 2; ++i)
                #pragma unroll
                for (int mt = 0; mt < 4; ++mt)
                    acc[i][mt] = __builtin_amdgcn_mfma_f32_16x16x32_bf16(af[i], bf[mt], acc[i][mt], 0, 0, 0);
        }
        #pragma unroll
        for (int i = 0; i < 2; ++i) {
            int n0 = (wave*2 + i)*16 + quad*4;
            float4 bv = *(const float4*)(nb2 + n0);
            #pragma unroll
            for (int mt = 0; mt < 4; ++mt) {
                int m = mt*16 + lane15;
                if (m < valid) {
                    float4 o;
                    o.x = acc[i][mt][0] + bv.x; o.y = acc[i][mt][1] + bv.y;
                    o.z = acc[i][mt][2] + bv.z; o.w = acc[i][mt][3] + bv.w;
                    *(float4*)(hbuf + (size_t)(r0 + m) * 128 + n0) = o;
                }
            }
        }
    }
}

// ---------------------------------------------------------------------------
// Edge MLP + scatter: 64 edges/block, MFMA, f32 atomic scatter into hbuf.
// grid = (ceil(NE/64), B)
// ---------------------------------------------------------------------------
__global__ __launch_bounds__(256) void edge_mlp_kernel(
    const float* __restrict__ x, const int* __restrict__ edges,
    const float* __restrict__ eb1, const float* __restrict__ eb2,
    const u16* __restrict__ frag, float* __restrict__ hbuf)
{
    __shared__ u16 ein[64 * EPITCH];   // 17408 B
    __shared__ u16 hid[64 * HPITCH];   // 33792 B
    __shared__ int us[64], vs[64];
    const int t = threadIdx.x;
    const int wave = t >> 6, l = t & 63, lane15 = l & 15, quad = l >> 4;
    const int b = blockIdx.y;
    const int e0 = blockIdx.x * 64;
    const int valid = min(64, NE - e0);

    if (t < 64) {
        int e = min(e0 + t, NE - 1);
        us[t] = edges[2 * e];
        vs[t] = edges[2 * e + 1];
    }
    __syncthreads();

    // gather + f32->bf16: ein[m][0:64]=x[u], [64:128]=x[v]
    #pragma unroll
    for (int it = 0; it < 8; ++it) {
        int i = t + it * 256;          // 0..2047
        int rh = i >> 4, c4 = i & 15;  // row-half, float4-col
        int m = rh >> 1, half = rh & 1;
        int node = half ? vs[m] : us[m];
        float4 g = ((const float4*)x)[(size_t)(b * NN + node) * 16 + c4];
        short4v s;
        s.x = (short)f2bf(g.x); s.y = (short)f2bf(g.y);
        s.z = (short)f2bf(g.z); s.w = (short)f2bf(g.w);
        *(short4v*)(ein + m * EPITCH + half * 64 + c4 * 4) = s;
    }
    __syncthreads();

    // GEMM1^T: K=128
    {
        f32x4 acc[4][4];
        #pragma unroll
        for (int i = 0; i < 4; ++i)
            #pragma unroll
            for (int mt = 0; mt < 4; ++mt) acc[i][mt] = f32x4{0.f,0.f,0.f,0.f};
        const u16* w1 = frag;            // [16][4][64][8]
        #pragma unroll
        for (int kblk = 0; kblk < 4; ++kblk) {
            short8 bf[4], af[4];
            #pragma unroll
            for (int mt = 0; mt < 4; ++mt)
                bf[mt] = *(const short8*)(ein + (mt*16 + lane15) * EPITCH + kblk*32 + quad*8);
            #pragma unroll
            for (int i = 0; i < 4; ++i)
                af[i] = *(const short8*)(w1 + (((wave*4 + i)*4 + kblk)*64 + l) * 8);
            #pragma unroll
            for (int i = 0; i < 4; ++i)
                #pragma unroll
                for (int mt = 0; mt < 4; ++mt)
                    acc[i][mt] = __builtin_amdgcn_mfma_f32_16x16x32_bf16(af[i], bf[mt], acc[i][mt], 0, 0, 0);
        }
        #pragma unroll
        for (int i = 0; i < 4; ++i) {
            int n0 = (wave*4 + i)*16 + quad*4;
            float4 bv = *(const float4*)(eb1 + n0);
            #pragma unroll
            for (int mt = 0; mt < 4; ++mt) {
                int m = mt*16 + lane15;
                short4v s;
                s.x = (short)f2bf(fmaxf(acc[i][mt][0] + bv.x, 0.f));
                s.y = (short)f2bf(fmaxf(acc[i][mt][1] + bv.y, 0.f));
                s.z = (short)f2bf(fmaxf(acc[i][mt][2] + bv.z, 0.f));
                s.w = (short)f2bf(fmaxf(acc[i][mt][3] + bv.w, 0.f));
                *(short4v*)(hid + m * HPITCH + n0) = s;
            }
        }
    }
    __syncthreads();

    // GEMM2^T: K=256, then atomic scatter-add to rows u and v
    {
        f32x4 acc[2][4];
        #pragma unroll
        for (int i = 0; i < 2; ++i)
            #pragma unroll
            for (int mt = 0; mt < 4; ++mt) acc[i][mt] = f32x4{0.f,0.f,0.f,0.f};
        const u16* w2 = frag + 49152;    // [8][8][64][8]
        #pragma unroll
        for (int kblk = 0; kblk < 8; ++kblk) {
            short8 bf[4], af[2];
            #pragma unroll
            for (int mt = 0; mt < 4; ++mt)
                bf[mt] = *(const short8*)(hid + (mt*16 + lane15) * HPITCH + kblk*32 + quad*8);
            #pragma unroll
            for (int i = 0; i < 2; ++i)
                af[i] = *(const short8*)(w2 + (((wave*2 + i)*8 + kblk)*64 + l) * 8);
            #pragma unroll
            for (int i = 0; i < 2; ++i)
                #pragma unroll
                for (int mt = 0; mt < 4; ++mt)
                    acc[i][mt] = __builtin_amdgcn_mfma_f32_16x16x32_bf16(af[i], bf[mt], acc[i][mt], 0, 0, 0);
        }
        #pragma unroll
        for (int i = 0; i < 2; ++i) {
            int n0 = (wave*2 + i)*16 + quad*4;
            float4 bv = *(const float4*)(eb2 + n0);
            #pragma unroll
            for (int mt = 0; mt < 4; ++mt) {
                int m = mt*16 + lane15;
                if (m < valid) {
                    float v0 = acc[i][mt][0] + bv.x;
                    float v1 = acc[i][mt][1] + bv.y;
                    float v2 = acc[i][mt][2] + bv.z;
                    float v3 = acc[i][mt][3] + bv.w;
                    float* pu = hbuf + (size_t)(b * NN + us[m]) * 128 + n0;
                    float* pv = hbuf + (size_t)(b * NN + vs[m]) * 128 + n0;
                    atomicAdd(pu + 0, v0); atomicAdd(pu + 1, v1);
                    atomicAdd(pu + 2, v2); atomicAdd(pu + 3, v3);
                    atomicAdd(pv + 0, v0); atomicAdd(pv + 1, v1);
                    atomicAdd(pv + 2, v2); atomicAdd(pv + 3, v3);
                }
            }
        }
    }
}

// ---------------------------------------------------------------------------
// Kernel 3: recon = hbuf @ dw + db -> f32 out. 64 rows/block. (f32 vector ALU,
// memory-bound: reads 51.2 MB.)
// ---------------------------------------------------------------------------
__global__ __launch_bounds__(256) void decode_kernel(
    const float* __restrict__ hbuf, const float* __restrict__ dw, const float* __restrict__ db,
    float* __restrict__ out)
{
    __shared__ float hs[64 * 128];    // 32 KB
    const int t  = threadIdx.x;
    const int r0 = blockIdx.x * 64;

    #pragma unroll
    for (int it = 0; it < 8; ++it) {
        int i = t + it * 256;         // 0..2047
        int m = i >> 5, c = i & 31;
        int r = r0 + m;
        float4 v = (r < BN) ? ((const float4*)hbuf)[(size_t)r * 32 + c]
                            : make_float4(0.f, 0.f, 0.f, 0.f);
        ((float4*)hs)[m * 32 + c] = v;
    }
    __syncthreads();

    const int d = t & 63, g = t >> 6;   // g wave-uniform
    float acc[16];
    #pragma unroll
    for (int i = 0; i < 16; ++i) acc[i] = 0.f;
    for (int k4 = 0; k4 < 32; ++k4) {
        float w0 = dw[(k4*4+0)*64 + d];
        float w1 = dw[(k4*4+1)*64 + d];
        float w2 = dw[(k4*4+2)*64 + d];
        float w3 = dw[(k4*4+3)*64 + d];
        #pragma unroll
        for (int mm = 0; mm < 16; ++mm) {
            float4 h4 = ((const float4*)hs)[(g*16+mm)*32 + k4];  // broadcast
            acc[mm] = fmaf(h4.x, w0, acc[mm]);
            acc[mm] = fmaf(h4.y, w1, acc[mm]);
            acc[mm] = fmaf(h4.z, w2, acc[mm]);
            acc[mm] = fmaf(h4.w, w3, acc[mm]);
        }
    }
    float bd = db[d];
    #pragma unroll
    for (int mm = 0; mm < 16; ++mm) {
        int r = r0 + g*16 + mm;
        if (r < BN) out[(size_t)r * 64 + d] = acc[mm] + bd;
    }
}

// ---------------------------------------------------------------------------
extern "C" void kernel_launch(void* const* d_in, const int* in_sizes, int n_in,
                              void* d_out, int out_size, void* d_ws, size_t ws_size,
                              hipStream_t stream) {
    const float* x     = (const float*)d_in[0];
    const int*   edges = (const int*)d_in[1];
    const float* ew1   = (const float*)d_in[2];
    const float* eb1   = (const float*)d_in[3];
    const float* ew2   = (const float*)d_in[4];
    const float* eb2   = (const float*)d_in[5];
    const float* nw1   = (const float*)d_in[6];
    const float* nb1   = (const float*)d_in[7];
    const float* nw2   = (const float*)d_in[8];
    const float* nb2   = (const float*)d_in[9];
    const float* dw    = (const float*)d_in[10];
    const float* db    = (const float*)d_in[11];

    float* hbuf = (float*)d_ws;                                    // 51.2 MB
    u16*   frag = (u16*)((char*)d_ws + (size_t)BN * 128 * 4);      // +224 KB

    swizzle_weights<<<448, 256, 0, stream>>>(ew1, nw1, ew2, nw2, frag);
    node_mlp_kernel<<<(BN + 63) / 64, 256, 0, stream>>>(x, nb1, nb2, frag, hbuf);
    edge_mlp_kernel<<<dim3((NE + 63) / 64, BB), 256, 0, stream>>>(x, edges, eb1, eb2, frag, hbuf);
    decode_kernel<<<(BN + 63) / 64, 256, 0, stream>>>(hbuf, dw, db, (float*)d_out);
}

// Round 6
// 807.787 us; speedup vs baseline: 4.2072x; 4.2072x over previous
//
#include <hip/hip_runtime.h>
#include <hip/hip_bf16.h>

// Problem constants
#define BB   2
#define NN   50000
#define BN   100000     // B*N
#define NE   500000

#define EPITCH 136      // ein LDS pitch (bf16 elems)
#define XPITCH 72       // node xs pitch
#define HPITCH 264      // hid LDS pitch

using u16 = unsigned short;
using u32 = unsigned int;
typedef __attribute__((ext_vector_type(8))) short short8;   // 8 x bf16 (4 VGPRs)
typedef __attribute__((ext_vector_type(4))) short short4v;  // 4 x bf16 (8B)
typedef __attribute__((ext_vector_type(4))) float f32x4;    // MFMA accumulator

__device__ __forceinline__ u16 f2bf(float f) {   // RNE f32 -> bf16 (finite inputs)
    union { float f; u32 u; } w; w.f = f;
    return (u16)((w.u + 0x7fffu + ((w.u >> 16) & 1u)) >> 16);
}

// ---------------------------------------------------------------------------
// CSR build over undirected incidences (node -> list of incident edge ids).
// cursor[] doubles as degree histogram, then as fill cursor.
// ---------------------------------------------------------------------------
__global__ __launch_bounds__(256) void csr_zero(int* __restrict__ cursor) {
    int i = blockIdx.x * 256 + threadIdx.x;
    if (i < NN) cursor[i] = 0;
}

__global__ __launch_bounds__(256) void csr_hist(const int* __restrict__ edges,
                                                int* __restrict__ cursor) {
    int e = blockIdx.x * 256 + threadIdx.x;
    if (e < NE) {
        atomicAdd(&cursor[edges[2*e]], 1);
        atomicAdd(&cursor[edges[2*e+1]], 1);
    }
}

// single block: exclusive scan of cursor(=deg) -> off[0..NN], reset cursor=off
__global__ __launch_bounds__(256) void csr_scan(int* __restrict__ cursor,
                                                int* __restrict__ off) {
    __shared__ int part[256];
    const int t = threadIdx.x;
    const int CH = (NN + 255) / 256;     // 196
    int s0 = t * CH, s1 = min(s0 + CH, NN);
    int sum = 0;
    for (int i = s0; i < s1; ++i) sum += cursor[i];
    part[t] = sum;
    __syncthreads();
    for (int d = 1; d < 256; d <<= 1) {  // Hillis-Steele inclusive scan
        int v = (t >= d) ? part[t - d] : 0;
        __syncthreads();
        part[t] += v;
        __syncthreads();
    }
    int prefix = (t == 0) ? 0 : part[t - 1];
    for (int i = s0; i < s1; ++i) {
        int d = cursor[i];
        off[i] = prefix;
        cursor[i] = prefix;
        prefix += d;
    }
    if (s1 == NN && s0 < NN) off[NN] = prefix;
}

__global__ __launch_bounds__(256) void csr_fill(const int* __restrict__ edges,
                                                int* __restrict__ cursor,
                                                int* __restrict__ inc) {
    int e = blockIdx.x * 256 + threadIdx.x;
    if (e < NE) {
        int pu = atomicAdd(&cursor[edges[2*e]], 1);   inc[pu] = e;
        int pv = atomicAdd(&cursor[edges[2*e+1]], 1); inc[pv] = e;
    }
}

// ---------------------------------------------------------------------------
// Weight pre-swizzle: A-fragment layout for mfma_f32_16x16x32_bf16.
// Regions (u16 offsets): w1e @0 (32768), w1n @32768 (16384),
//                        w2e @49152 (32768), w2n @81920 (32768).
// ---------------------------------------------------------------------------
__global__ __launch_bounds__(256) void swizzle_weights(
    const float* __restrict__ ew1, const float* __restrict__ nw1,
    const float* __restrict__ ew2, const float* __restrict__ nw2,
    u16* __restrict__ frag)
{
    int idx = blockIdx.x * 256 + threadIdx.x;   // 0 .. 114687
    if (idx >= 114688) return;
    const float* src; int KB, NCOL, local;
    if (idx < 32768)      { local = idx;         src = ew1; KB = 4; NCOL = 256; }
    else if (idx < 49152) { local = idx - 32768; src = nw1; KB = 2; NCOL = 256; }
    else if (idx < 81920) { local = idx - 49152; src = ew2; KB = 8; NCOL = 128; }
    else                  { local = idx - 81920; src = nw2; KB = 8; NCOL = 128; }
    int j = local & 7, l = (local >> 3) & 63, rest = local >> 9;
    int kblk = rest % KB, ntile = rest / KB;
    int n = ntile * 16 + (l & 15);
    int k = kblk * 32 + ((l >> 4) << 3) + j;
    frag[idx] = f2bf(src[k * NCOL + n]);
}

// ---------------------------------------------------------------------------
// Node MLP: hbuf[r][:] = relu(x[r]@nw1+nb1)@nw2+nb2, 64 rows/block, MFMA.
// ---------------------------------------------------------------------------
__global__ __launch_bounds__(256) void node_mlp_kernel(
    const float* __restrict__ x, const float* __restrict__ nb1,
    const float* __restrict__ nb2, const u16* __restrict__ frag,
    float* __restrict__ hbuf)
{
    __shared__ u16 xs[64 * XPITCH];    // 9216 B
    __shared__ u16 hid[64 * HPITCH];   // 33792 B
    const int t = threadIdx.x;
    const int wave = t >> 6, l = t & 63, lane15 = l & 15, quad = l >> 4;
    const int r0 = blockIdx.x * 64;
    const int valid = min(64, BN - r0);

    #pragma unroll
    for (int it = 0; it < 4; ++it) {
        int i = t + it * 256;
        int m = i >> 4, c4 = i & 15;
        int row = min(r0 + m, BN - 1);
        float4 g = ((const float4*)x)[(size_t)row * 16 + c4];
        short4v s;
        s.x = (short)f2bf(g.x); s.y = (short)f2bf(g.y);
        s.z = (short)f2bf(g.z); s.w = (short)f2bf(g.w);
        *(short4v*)(xs + m * XPITCH + c4 * 4) = s;
    }
    __syncthreads();

    {   // GEMM1^T, K=64
        f32x4 acc[4][4];
        #pragma unroll
        for (int i = 0; i < 4; ++i)
            #pragma unroll
            for (int mt = 0; mt < 4; ++mt) acc[i][mt] = f32x4{0.f,0.f,0.f,0.f};
        const u16* w1 = frag + 32768;    // [16][2][64][8]
        #pragma unroll
        for (int kblk = 0; kblk < 2; ++kblk) {
            short8 bf[4], af[4];
            #pragma unroll
            for (int mt = 0; mt < 4; ++mt)
                bf[mt] = *(const short8*)(xs + (mt*16 + lane15) * XPITCH + kblk*32 + quad*8);
            #pragma unroll
            for (int i = 0; i < 4; ++i)
                af[i] = *(const short8*)(w1 + (((wave*4 + i)*2 + kblk)*64 + l) * 8);
            #pragma unroll
            for (int i = 0; i < 4; ++i)
                #pragma unroll
                for (int mt = 0; mt < 4; ++mt)
                    acc[i][mt] = __builtin_amdgcn_mfma_f32_16x16x32_bf16(af[i], bf[mt], acc[i][mt], 0, 0, 0);
        }
        #pragma unroll
        for (int i = 0; i < 4; ++i) {
            int n0 = (wave*4 + i)*16 + quad*4;
            float4 bv = *(const float4*)(nb1 + n0);
            #pragma unroll
            for (int mt = 0; mt < 4; ++mt) {
                int m = mt*16 + lane15;
                short4v s;
                s.x = (short)f2bf(fmaxf(acc[i][mt][0] + bv.x, 0.f));
                s.y = (short)f2bf(fmaxf(acc[i][mt][1] + bv.y, 0.f));
                s.z = (short)f2bf(fmaxf(acc[i][mt][2] + bv.z, 0.f));
                s.w = (short)f2bf(fmaxf(acc[i][mt][3] + bv.w, 0.f));
                *(short4v*)(hid + m * HPITCH + n0) = s;
            }
        }
    }
    __syncthreads();

    {   // GEMM2^T, K=256 -> f32 store
        f32x4 acc[2][4];
        #pragma unroll
        for (int i = 0; i < 2; ++i)
            #pragma unroll
            for (int mt = 0; mt < 4; ++mt) acc[i][mt] = f32x4{0.f,0.f,0.f,0.f};
        const u16* w2 = frag + 81920;    // [8][8][64][8]
        #pragma unroll
        for (int kblk = 0; kblk < 8; ++kblk) {
            short8 bf[4], af[2];
            #pragma unroll
            for (int mt = 0; mt < 4; ++mt)
                bf[mt] = *(const short8*)(hid + (mt*16 + lane15) * HPITCH + kblk*32 + quad*8);
            #pragma unroll
            for (int i = 0; i < 2; ++i)
                af[i] = *(const short8*)(w2 + (((wave*2 + i)*8 + kblk)*64 + l) * 8);
            #pragma unroll
            for (int i = 0; i < 2; ++i)
                #pragma unroll
                for (int mt = 0; mt < 4; ++mt)
                    acc[i][mt] = __builtin_amdgcn_mfma_f32_16x16x32_bf16(af[i], bf[mt], acc[i][mt], 0, 0, 0);
        }
        #pragma unroll
        for (int i = 0; i < 2; ++i) {
            int n0 = (wave*2 + i)*16 + quad*4;
            float4 bv = *(const float4*)(nb2 + n0);
            #pragma unroll
            for (int mt = 0; mt < 4; ++mt) {
                int m = mt*16 + lane15;
                if (m < valid) {
                    float4 o;
                    o.x = acc[i][mt][0] + bv.x; o.y = acc[i][mt][1] + bv.y;
                    o.z = acc[i][mt][2] + bv.z; o.w = acc[i][mt][3] + bv.w;
                    *(float4*)(hbuf + (size_t)(r0 + m) * 128 + n0) = o;
                }
            }
        }
    }
}

// ---------------------------------------------------------------------------
// Phase A: edge MLP -> emb (bf16 [NE][128]) for batch b. No atomics.
// ---------------------------------------------------------------------------
__global__ __launch_bounds__(256) void edge_emb_kernel(
    const float* __restrict__ x, const int* __restrict__ edges,
    const float* __restrict__ eb1, const float* __restrict__ eb2,
    const u16* __restrict__ frag, u16* __restrict__ emb, int b)
{
    __shared__ u16 ein[64 * EPITCH];   // 17408 B
    __shared__ u16 hid[64 * HPITCH];   // 33792 B
    __shared__ int us[64], vs[64];
    const int t = threadIdx.x;
    const int wave = t >> 6, l = t & 63, lane15 = l & 15, quad = l >> 4;
    const int e0 = blockIdx.x * 64;
    const int valid = min(64, NE - e0);

    if (t < 64) {
        int e = min(e0 + t, NE - 1);
        us[t] = edges[2 * e];
        vs[t] = edges[2 * e + 1];
    }
    __syncthreads();

    #pragma unroll
    for (int it = 0; it < 8; ++it) {
        int i = t + it * 256;          // 0..2047
        int rh = i >> 4, c4 = i & 15;
        int m = rh >> 1, half = rh & 1;
        int node = half ? vs[m] : us[m];
        float4 g = ((const float4*)x)[(size_t)(b * NN + node) * 16 + c4];
        short4v s;
        s.x = (short)f2bf(g.x); s.y = (short)f2bf(g.y);
        s.z = (short)f2bf(g.z); s.w = (short)f2bf(g.w);
        *(short4v*)(ein + m * EPITCH + half * 64 + c4 * 4) = s;
    }
    __syncthreads();

    {   // GEMM1^T, K=128
        f32x4 acc[4][4];
        #pragma unroll
        for (int i = 0; i < 4; ++i)
            #pragma unroll
            for (int mt = 0; mt < 4; ++mt) acc[i][mt] = f32x4{0.f,0.f,0.f,0.f};
        const u16* w1 = frag;            // [16][4][64][8]
        #pragma unroll
        for (int kblk = 0; kblk < 4; ++kblk) {
            short8 bf[4], af[4];
            #pragma unroll
            for (int mt = 0; mt < 4; ++mt)
                bf[mt] = *(const short8*)(ein + (mt*16 + lane15) * EPITCH + kblk*32 + quad*8);
            #pragma unroll
            for (int i = 0; i < 4; ++i)
                af[i] = *(const short8*)(w1 + (((wave*4 + i)*4 + kblk)*64 + l) * 8);
            #pragma unroll
            for (int i = 0; i < 4; ++i)
                #pragma unroll
                for (int mt = 0; mt < 4; ++mt)
                    acc[i][mt] = __builtin_amdgcn_mfma_f32_16x16x32_bf16(af[i], bf[mt], acc[i][mt], 0, 0, 0);
        }
        #pragma unroll
        for (int i = 0; i < 4; ++i) {
            int n0 = (wave*4 + i)*16 + quad*4;
            float4 bv = *(const float4*)(eb1 + n0);
            #pragma unroll
            for (int mt = 0; mt < 4; ++mt) {
                int m = mt*16 + lane15;
                short4v s;
                s.x = (short)f2bf(fmaxf(acc[i][mt][0] + bv.x, 0.f));
                s.y = (short)f2bf(fmaxf(acc[i][mt][1] + bv.y, 0.f));
                s.z = (short)f2bf(fmaxf(acc[i][mt][2] + bv.z, 0.f));
                s.w = (short)f2bf(fmaxf(acc[i][mt][3] + bv.w, 0.f));
                *(short4v*)(hid + m * HPITCH + n0) = s;
            }
        }
    }
    __syncthreads();

    {   // GEMM2^T, K=256 -> bf16 emb store
        f32x4 acc[2][4];
        #pragma unroll
        for (int i = 0; i < 2; ++i)
            #pragma unroll
            for (int mt = 0; mt < 4; ++mt) acc[i][mt] = f32x4{0.f,0.f,0.f,0.f};
        const u16* w2 = frag + 49152;    // [8][8][64][8]
        #pragma unroll
        for (int kblk = 0; kblk < 8; ++kblk) {
            short8 bf[4], af[2];
            #pragma unroll
            for (int mt = 0; mt < 4; ++mt)
                bf[mt] = *(const short8*)(hid + (mt*16 + lane15) * HPITCH + kblk*32 + quad*8);
            #pragma unroll
            for (int i = 0; i < 2; ++i)
                af[i] = *(const short8*)(w2 + (((wave*2 + i)*8 + kblk)*64 + l) * 8);
            #pragma unroll
            for (int i = 0; i < 2; ++i)
                #pragma unroll
                for (int mt = 0; mt < 4; ++mt)
                    acc[i][mt] = __builtin_amdgcn_mfma_f32_16x16x32_bf16(af[i], bf[mt], acc[i][mt], 0, 0, 0);
        }
        #pragma unroll
        for (int i = 0; i < 2; ++i) {
            int n0 = (wave*2 + i)*16 + quad*4;
            float4 bv = *(const float4*)(eb2 + n0);
            #pragma unroll
            for (int mt = 0; mt < 4; ++mt) {
                int m = mt*16 + lane15;
                if (m < valid) {
                    short4v s;
                    s.x = (short)f2bf(acc[i][mt][0] + bv.x);
                    s.y = (short)f2bf(acc[i][mt][1] + bv.y);
                    s.z = (short)f2bf(acc[i][mt][2] + bv.z);
                    s.w = (short)f2bf(acc[i][mt][3] + bv.w);
                    *(short4v*)(emb + (size_t)(e0 + m) * 128 + n0) = s;
                }
            }
        }
    }
}

// ---------------------------------------------------------------------------
// Phase B: per-node gather of incident edge embeddings; += into hbuf.
// One wave per node; lane l covers columns 2l, 2l+1 (256B coalesced row reads).
// ---------------------------------------------------------------------------
__global__ __launch_bounds__(256) void gather_kernel(
    const u32* __restrict__ emb32, const int* __restrict__ off,
    const int* __restrict__ inc, float* __restrict__ hbuf, int b)
{
    const int t = threadIdx.x, wave = t >> 6, l = t & 63;
    const int n = blockIdx.x * 4 + wave;
    const int base = off[n], cnt = off[n + 1] - base;
    if (cnt == 0) return;                   // wave-uniform
    float a0 = 0.f, a1 = 0.f;
    for (int j0 = 0; j0 < cnt; j0 += 64) {
        int ev = inc[min(base + j0 + l, 2 * NE - 1)];
        int lim = min(64, cnt - j0);
        for (int i = 0; i < lim; ++i) {
            int e = __shfl(ev, i);
            u32 w = emb32[(size_t)e * 64 + l];
            union { u32 u; float f; } lo, hi;
            lo.u = w << 16; hi.u = w & 0xffff0000u;
            a0 += lo.f; a1 += hi.f;
        }
    }
    float2* p = (float2*)(hbuf + (size_t)(b * NN + n) * 128 + 2 * l);
    float2 h = *p; h.x += a0; h.y += a1; *p = h;
}

// ---------------------------------------------------------------------------
// Decode: recon = hbuf @ dw + db -> f32 out. 64 rows/block.
// ---------------------------------------------------------------------------
__global__ __launch_bounds__(256) void decode_kernel(
    const float* __restrict__ hbuf, const float* __restrict__ dw, const float* __restrict__ db,
    float* __restrict__ out)
{
    __shared__ float hs[64 * 128];    // 32 KB
    const int t  = threadIdx.x;
    const int r0 = blockIdx.x * 64;

    #pragma unroll
    for (int it = 0; it < 8; ++it) {
        int i = t + it * 256;
        int m = i >> 5, c = i & 31;
        int r = r0 + m;
        float4 v = (r < BN) ? ((const float4*)hbuf)[(size_t)r * 32 + c]
                            : make_float4(0.f, 0.f, 0.f, 0.f);
        ((float4*)hs)[m * 32 + c] = v;
    }
    __syncthreads();

    const int d = t & 63, g = t >> 6;
    float acc[16];
    #pragma unroll
    for (int i = 0; i < 16; ++i) acc[i] = 0.f;
    for (int k4 = 0; k4 < 32; ++k4) {
        float w0 = dw[(k4*4+0)*64 + d];
        float w1 = dw[(k4*4+1)*64 + d];
        float w2 = dw[(k4*4+2)*64 + d];
        float w3 = dw[(k4*4+3)*64 + d];
        #pragma unroll
        for (int mm = 0; mm < 16; ++mm) {
            float4 h4 = ((const float4*)hs)[(g*16+mm)*32 + k4];
            acc[mm] = fmaf(h4.x, w0, acc[mm]);
            acc[mm] = fmaf(h4.y, w1, acc[mm]);
            acc[mm] = fmaf(h4.z, w2, acc[mm]);
            acc[mm] = fmaf(h4.w, w3, acc[mm]);
        }
    }
    float bd = db[d];
    #pragma unroll
    for (int mm = 0; mm < 16; ++mm) {
        int r = r0 + g*16 + mm;
        if (r < BN) out[(size_t)r * 64 + d] = acc[mm] + bd;
    }
}

// ---------------------------------------------------------------------------
extern "C" void kernel_launch(void* const* d_in, const int* in_sizes, int n_in,
                              void* d_out, int out_size, void* d_ws, size_t ws_size,
                              hipStream_t stream) {
    const float* x     = (const float*)d_in[0];
    const int*   edges = (const int*)d_in[1];
    const float* ew1   = (const float*)d_in[2];
    const float* eb1   = (const float*)d_in[3];
    const float* ew2   = (const float*)d_in[4];
    const float* eb2   = (const float*)d_in[5];
    const float* nw1   = (const float*)d_in[6];
    const float* nb1   = (const float*)d_in[7];
    const float* nw2   = (const float*)d_in[8];
    const float* nb2   = (const float*)d_in[9];
    const float* dw    = (const float*)d_in[10];
    const float* db    = (const float*)d_in[11];

    // Workspace layout (aligned to 512B):
    char* w = (char*)d_ws;
    size_t o = 0;
    auto take = [&](size_t bytes) { char* p = w + o; o = (o + bytes + 511) & ~(size_t)511; return p; };
    float* hbuf   = (float*)take((size_t)BN * 128 * 4);       // 51.2 MB
    u16*   frag   = (u16*)  take(114688 * 2);                 // 224 KB
    int*   cursor = (int*)  take((size_t)NN * 4);             // 200 KB
    int*   off    = (int*)  take((size_t)(NN + 1) * 4);       // 200 KB
    int*   inc    = (int*)  take((size_t)2 * NE * 4);         // 4 MB
    u16*   emb    = (u16*)  take((size_t)NE * 128 * 2);       // 128 MB (per-batch reuse)

    // CSR build (edges are batch-invariant)
    csr_zero<<<(NN + 255) / 256, 256, 0, stream>>>(cursor);
    csr_hist<<<(NE + 255) / 256, 256, 0, stream>>>(edges, cursor);
    csr_scan<<<1, 256, 0, stream>>>(cursor, off);
    csr_fill<<<(NE + 255) / 256, 256, 0, stream>>>(edges, cursor, inc);

    swizzle_weights<<<448, 256, 0, stream>>>(ew1, nw1, ew2, nw2, frag);
    node_mlp_kernel<<<(BN + 63) / 64, 256, 0, stream>>>(x, nb1, nb2, frag, hbuf);

    for (int b = 0; b < BB; ++b) {
        edge_emb_kernel<<<(NE + 63) / 64, 256, 0, stream>>>(x, edges, eb1, eb2, frag, emb, b);
        gather_kernel<<<NN / 4, 256, 0, stream>>>((const u32*)emb, off, inc, hbuf, b);
    }

    decode_kernel<<<(BN + 63) / 64, 256, 0, stream>>>(hbuf, dw, db, (float*)d_out);
}

// Round 7
// 622.954 us; speedup vs baseline: 5.4555x; 1.2967x over previous
//
#include <hip/hip_runtime.h>
#include <hip/hip_bf16.h>

// Problem constants
#define BB   2
#define NN   50000
#define BN   100000     // B*N
#define NE   500000

#define EPITCH 136      // ein LDS pitch (bf16 elems): 68 dwords = 4 mod 32 banks
#define XPITCH 72       // node xs pitch: 36 dwords = 4 mod 32
#define HPITCH 264      // hid LDS pitch: 132 dwords = 4 mod 32

using u16 = unsigned short;
using u32 = unsigned int;
typedef __attribute__((ext_vector_type(8))) short short8;   // 8 x bf16 (4 VGPRs)
typedef __attribute__((ext_vector_type(4))) short short4v;  // 4 x bf16 (8B)
typedef __attribute__((ext_vector_type(4))) float f32x4;    // MFMA accumulator

__device__ __forceinline__ u16 f2bf(float f) {   // RNE f32 -> bf16 (finite inputs)
    union { float f; u32 u; } w; w.f = f;
    return (u16)((w.u + 0x7fffu + ((w.u >> 16) & 1u)) >> 16);
}

// ---------------------------------------------------------------------------
// CSR build over undirected incidences (node -> incident edge ids).
// ---------------------------------------------------------------------------
__global__ __launch_bounds__(256) void csr_zero(int* __restrict__ cursor) {
    int i = blockIdx.x * 256 + threadIdx.x;
    if (i < NN) cursor[i] = 0;
}

__global__ __launch_bounds__(256) void csr_hist(const int* __restrict__ edges,
                                                int* __restrict__ cursor) {
    int e = blockIdx.x * 256 + threadIdx.x;
    if (e < NE) {
        atomicAdd(&cursor[edges[2*e]], 1);
        atomicAdd(&cursor[edges[2*e+1]], 1);
    }
}

__global__ __launch_bounds__(256) void csr_scan(int* __restrict__ cursor,
                                                int* __restrict__ off) {
    __shared__ int part[256];
    const int t = threadIdx.x;
    const int CH = (NN + 255) / 256;     // 196
    int s0 = t * CH, s1 = min(s0 + CH, NN);
    int sum = 0;
    for (int i = s0; i < s1; ++i) sum += cursor[i];
    part[t] = sum;
    __syncthreads();
    for (int d = 1; d < 256; d <<= 1) {
        int v = (t >= d) ? part[t - d] : 0;
        __syncthreads();
        part[t] += v;
        __syncthreads();
    }
    int prefix = (t == 0) ? 0 : part[t - 1];
    for (int i = s0; i < s1; ++i) {
        int d = cursor[i];
        off[i] = prefix;
        cursor[i] = prefix;
        prefix += d;
    }
    if (s1 == NN && s0 < NN) off[NN] = prefix;
}

__global__ __launch_bounds__(256) void csr_fill(const int* __restrict__ edges,
                                                int* __restrict__ cursor,
                                                int* __restrict__ inc) {
    int e = blockIdx.x * 256 + threadIdx.x;
    if (e < NE) {
        int pu = atomicAdd(&cursor[edges[2*e]], 1);   inc[pu] = e;
        int pv = atomicAdd(&cursor[edges[2*e+1]], 1); inc[pv] = e;
    }
}

// ---------------------------------------------------------------------------
// W1 pre-swizzle: A-fragment layout for mfma_f32_16x16x32_bf16.
// frag[ntile][kblk][lane][j] = W[k][n], n=ntile*16+(l&15), k=kblk*32+(l>>4)*8+j.
// Regions (u16): w1e @0 (32768 = [16][4][64][8]), w1n @32768 (16384 = [16][2][64][8]),
//                w2e' @49152 (16384 = [4][8][64][8]), w2n' @65536 (16384).
// ---------------------------------------------------------------------------
__global__ __launch_bounds__(256) void swizzle_w1(
    const float* __restrict__ ew1, const float* __restrict__ nw1,
    u16* __restrict__ frag)
{
    int idx = blockIdx.x * 256 + threadIdx.x;   // 0 .. 49151
    if (idx >= 49152) return;
    const float* src; int KB, local;
    if (idx < 32768) { local = idx;         src = ew1; KB = 4; }
    else             { local = idx - 32768; src = nw1; KB = 2; }
    int j = local & 7, l = (local >> 3) & 63, rest = local >> 9;
    int kblk = rest % KB, ntile = rest / KB;
    int n = ntile * 16 + (l & 15);
    int k = kblk * 32 + ((l >> 4) << 3) + j;
    frag[idx] = f2bf(src[k * 256 + n]);
}

// Fused W2' = W2 @ dw (256x64), straight into A-frag layout.
__global__ __launch_bounds__(256) void fuse_w2(
    const float* __restrict__ ew2, const float* __restrict__ nw2,
    const float* __restrict__ dw, u16* __restrict__ frag)
{
    int idx = blockIdx.x * 256 + threadIdx.x;   // 0 .. 32767
    if (idx >= 32768) return;
    const float* src = (idx < 16384) ? ew2 : nw2;
    int local = idx & 16383;
    int j = local & 7, l = (local >> 3) & 63, rest = local >> 9;  // 0..31
    int kblk = rest & 7, ntile = rest >> 3;
    int n = ntile * 16 + (l & 15);              // 0..63
    int k = kblk * 32 + ((l >> 4) << 3) + j;    // 0..255
    float s = 0.f;
    for (int jj = 0; jj < 128; ++jj) s = fmaf(src[k * 128 + jj], dw[jj * 64 + n], s);
    frag[49152 + idx] = f2bf(s);
}

// bias2[0:64] = eb2@dw ; bias2[64:128] = nb2@dw + db
__global__ __launch_bounds__(64) void fuse_bias(
    const float* __restrict__ eb2, const float* __restrict__ nb2,
    const float* __restrict__ dw, const float* __restrict__ db,
    float* __restrict__ bias2)
{
    int d = threadIdx.x;
    float se = 0.f, sn = 0.f;
    for (int j = 0; j < 128; ++j) {
        float w = dw[j * 64 + d];
        se = fmaf(eb2[j], w, se);
        sn = fmaf(nb2[j], w, sn);
    }
    bias2[d] = se;
    bias2[64 + d] = sn + db[d];
}

// x (f32) -> xbf (bf16), once.
__global__ __launch_bounds__(256) void x_to_bf16(const float* __restrict__ x,
                                                 u16* __restrict__ xbf)
{
    int i = blockIdx.x * 256 + threadIdx.x;    // float4 groups
    if (i >= BN * 16) return;
    float4 g = ((const float4*)x)[i];
    short4v s;
    s.x = (short)f2bf(g.x); s.y = (short)f2bf(g.y);
    s.z = (short)f2bf(g.z); s.w = (short)f2bf(g.w);
    *(short4v*)(xbf + (size_t)i * 4) = s;
}

// ---------------------------------------------------------------------------
// Node MLP (dw-fused): out[r][0:64] = relu(x[r]@nw1+nb1)@(nw2@dw) + (nb2@dw+db)
// 64 rows/block, 256 threads, MFMA. Writes d_out base term directly.
// ---------------------------------------------------------------------------
__global__ __launch_bounds__(256) void node_mlp_kernel(
    const u16* __restrict__ xbf, const float* __restrict__ nb1,
    const float* __restrict__ bias2, const u16* __restrict__ frag,
    float* __restrict__ out)
{
    __shared__ u16 xs[64 * XPITCH];    // 9216 B
    __shared__ u16 hid[64 * HPITCH];   // 33792 B
    const int t = threadIdx.x;
    const int wave = t >> 6, l = t & 63, lane15 = l & 15, quad = l >> 4;
    const int r0 = blockIdx.x * 64;
    const int valid = min(64, BN - r0);

    // stage xbf tile: 64 rows x 8 uint4, 2 per thread
    #pragma unroll
    for (int it = 0; it < 2; ++it) {
        int i = t + it * 256;          // 0..511
        int m = i >> 3, c8 = i & 7;
        int row = min(r0 + m, BN - 1);
        uint4 q = ((const uint4*)xbf)[(size_t)row * 8 + c8];
        *(uint4*)(xs + m * XPITCH + c8 * 8) = q;
    }
    __syncthreads();

    {   // GEMM1^T, K=64
        f32x4 acc[4][4];
        #pragma unroll
        for (int i = 0; i < 4; ++i)
            #pragma unroll
            for (int mt = 0; mt < 4; ++mt) acc[i][mt] = f32x4{0.f,0.f,0.f,0.f};
        const u16* w1 = frag + 32768;    // [16][2][64][8]
        #pragma unroll
        for (int kblk = 0; kblk < 2; ++kblk) {
            short8 bf[4], af[4];
            #pragma unroll
            for (int mt = 0; mt < 4; ++mt)
                bf[mt] = *(const short8*)(xs + (mt*16 + lane15) * XPITCH + kblk*32 + quad*8);
            #pragma unroll
            for (int i = 0; i < 4; ++i)
                af[i] = *(const short8*)(w1 + (((wave*4 + i)*2 + kblk)*64 + l) * 8);
            #pragma unroll
            for (int i = 0; i < 4; ++i)
                #pragma unroll
                for (int mt = 0; mt < 4; ++mt)
                    acc[i][mt] = __builtin_amdgcn_mfma_f32_16x16x32_bf16(af[i], bf[mt], acc[i][mt], 0, 0, 0);
        }
        #pragma unroll
        for (int i = 0; i < 4; ++i) {
            int n0 = (wave*4 + i)*16 + quad*4;
            float4 bv = *(const float4*)(nb1 + n0);
            #pragma unroll
            for (int mt = 0; mt < 4; ++mt) {
                int m = mt*16 + lane15;
                short4v s;
                s.x = (short)f2bf(fmaxf(acc[i][mt][0] + bv.x, 0.f));
                s.y = (short)f2bf(fmaxf(acc[i][mt][1] + bv.y, 0.f));
                s.z = (short)f2bf(fmaxf(acc[i][mt][2] + bv.z, 0.f));
                s.w = (short)f2bf(fmaxf(acc[i][mt][3] + bv.w, 0.f));
                *(short4v*)(hid + m * HPITCH + n0) = s;
            }
        }
    }
    __syncthreads();

    {   // fused GEMM2^T: N=64, K=256 -> f32 out
        f32x4 acc[4];
        #pragma unroll
        for (int mt = 0; mt < 4; ++mt) acc[mt] = f32x4{0.f,0.f,0.f,0.f};
        const u16* w2 = frag + 65536;    // [4][8][64][8], ntile = wave
        #pragma unroll
        for (int kblk = 0; kblk < 8; ++kblk) {
            short8 bf[4], af;
            #pragma unroll
            for (int mt = 0; mt < 4; ++mt)
                bf[mt] = *(const short8*)(hid + (mt*16 + lane15) * HPITCH + kblk*32 + quad*8);
            af = *(const short8*)(w2 + ((wave*8 + kblk)*64 + l) * 8);
            #pragma unroll
            for (int mt = 0; mt < 4; ++mt)
                acc[mt] = __builtin_amdgcn_mfma_f32_16x16x32_bf16(af, bf[mt], acc[mt], 0, 0, 0);
        }
        int n0 = wave*16 + quad*4;
        float4 bv = *(const float4*)(bias2 + 64 + n0);
        #pragma unroll
        for (int mt = 0; mt < 4; ++mt) {
            int m = mt*16 + lane15;
            if (m < valid) {
                float4 o;
                o.x = acc[mt][0] + bv.x; o.y = acc[mt][1] + bv.y;
                o.z = acc[mt][2] + bv.z; o.w = acc[mt][3] + bv.w;
                *(float4*)(out + (size_t)(r0 + m) * 64 + n0) = o;
            }
        }
    }
}

// ---------------------------------------------------------------------------
// Edge MLP (dw-fused) -> edec (bf16 [NE][64]) for batch b. No atomics.
// ---------------------------------------------------------------------------
__global__ __launch_bounds__(256) void edge_emb_kernel(
    const u16* __restrict__ xbf, const int* __restrict__ edges,
    const float* __restrict__ eb1, const float* __restrict__ bias2,
    const u16* __restrict__ frag, u16* __restrict__ edec, int b)
{
    __shared__ u16 ein[64 * EPITCH];   // 17408 B
    __shared__ u16 hid[64 * HPITCH];   // 33792 B
    __shared__ int us[64], vs[64];
    const int t = threadIdx.x;
    const int wave = t >> 6, l = t & 63, lane15 = l & 15, quad = l >> 4;
    const int e0 = blockIdx.x * 64;
    const int valid = min(64, NE - e0);

    if (t < 64) {
        int e = min(e0 + t, NE - 1);
        us[t] = edges[2 * e];
        vs[t] = edges[2 * e + 1];
    }
    __syncthreads();

    // gather bf16 rows: 64 edges x 2 halves x 8 uint4 = 1024, 4 per thread
    #pragma unroll
    for (int it = 0; it < 4; ++it) {
        int i = t + it * 256;           // 0..1023
        int m = i >> 4, c = i & 15;
        int half = c >> 3, c8 = c & 7;
        int node = half ? vs[m] : us[m];
        uint4 q = ((const uint4*)xbf)[(size_t)(b * NN + node) * 8 + c8];
        *(uint4*)(ein + m * EPITCH + half * 64 + c8 * 8) = q;
    }
    __syncthreads();

    {   // GEMM1^T, K=128
        f32x4 acc[4][4];
        #pragma unroll
        for (int i = 0; i < 4; ++i)
            #pragma unroll
            for (int mt = 0; mt < 4; ++mt) acc[i][mt] = f32x4{0.f,0.f,0.f,0.f};
        const u16* w1 = frag;            // [16][4][64][8]
        #pragma unroll
        for (int kblk = 0; kblk < 4; ++kblk) {
            short8 bf[4], af[4];
            #pragma unroll
            for (int mt = 0; mt < 4; ++mt)
                bf[mt] = *(const short8*)(ein + (mt*16 + lane15) * EPITCH + kblk*32 + quad*8);
            #pragma unroll
            for (int i = 0; i < 4; ++i)
                af[i] = *(const short8*)(w1 + (((wave*4 + i)*4 + kblk)*64 + l) * 8);
            #pragma unroll
            for (int i = 0; i < 4; ++i)
                #pragma unroll
                for (int mt = 0; mt < 4; ++mt)
                    acc[i][mt] = __builtin_amdgcn_mfma_f32_16x16x32_bf16(af[i], bf[mt], acc[i][mt], 0, 0, 0);
        }
        #pragma unroll
        for (int i = 0; i < 4; ++i) {
            int n0 = (wave*4 + i)*16 + quad*4;
            float4 bv = *(const float4*)(eb1 + n0);
            #pragma unroll
            for (int mt = 0; mt < 4; ++mt) {
                int m = mt*16 + lane15;
                short4v s;
                s.x = (short)f2bf(fmaxf(acc[i][mt][0] + bv.x, 0.f));
                s.y = (short)f2bf(fmaxf(acc[i][mt][1] + bv.y, 0.f));
                s.z = (short)f2bf(fmaxf(acc[i][mt][2] + bv.z, 0.f));
                s.w = (short)f2bf(fmaxf(acc[i][mt][3] + bv.w, 0.f));
                *(short4v*)(hid + m * HPITCH + n0) = s;
            }
        }
    }
    __syncthreads();

    {   // fused GEMM2^T: N=64, K=256 -> bf16 edec store
        f32x4 acc[4];
        #pragma unroll
        for (int mt = 0; mt < 4; ++mt) acc[mt] = f32x4{0.f,0.f,0.f,0.f};
        const u16* w2 = frag + 49152;    // [4][8][64][8], ntile = wave
        #pragma unroll
        for (int kblk = 0; kblk < 8; ++kblk) {
            short8 bf[4], af;
            #pragma unroll
            for (int mt = 0; mt < 4; ++mt)
                bf[mt] = *(const short8*)(hid + (mt*16 + lane15) * HPITCH + kblk*32 + quad*8);
            af = *(const short8*)(w2 + ((wave*8 + kblk)*64 + l) * 8);
            #pragma unroll
            for (int mt = 0; mt < 4; ++mt)
                acc[mt] = __builtin_amdgcn_mfma_f32_16x16x32_bf16(af, bf[mt], acc[mt], 0, 0, 0);
        }
        int n0 = wave*16 + quad*4;
        float4 bv = *(const float4*)(bias2 + n0);
        #pragma unroll
        for (int mt = 0; mt < 4; ++mt) {
            int m = mt*16 + lane15;
            if (m < valid) {
                short4v s;
                s.x = (short)f2bf(acc[mt][0] + bv.x);
                s.y = (short)f2bf(acc[mt][1] + bv.y);
                s.z = (short)f2bf(acc[mt][2] + bv.z);
                s.w = (short)f2bf(acc[mt][3] + bv.w);
                *(short4v*)(edec + (size_t)(e0 + m) * 64 + n0) = s;
            }
        }
    }
}

// ---------------------------------------------------------------------------
// Gather: out[b][n][:] += sum of edec rows of incident edges.
// One wave per node; 2 edges per iteration (32 lanes each, row = 32 u32).
// ---------------------------------------------------------------------------
__global__ __launch_bounds__(256) void gather_kernel(
    const u32* __restrict__ edec32, const int* __restrict__ off,
    const int* __restrict__ inc, float* __restrict__ out, int b)
{
    const int t = threadIdx.x, wave = t >> 6, l = t & 63;
    const int n = blockIdx.x * 4 + wave;
    const int base = off[n], cnt = off[n + 1] - base;
    if (cnt == 0) return;                   // wave-uniform
    const int half = l >> 5, c = l & 31;
    float a0 = 0.f, a1 = 0.f;
    for (int j0 = 0; j0 < cnt; j0 += 64) {
        int ev = inc[min(base + j0 + l, 2 * NE - 1)];
        int lim = min(64, cnt - j0);
        for (int i = 0; i < lim; i += 2) {
            int sel = i + half;
            int e = __shfl(ev, sel);
            u32 w = edec32[(size_t)e * 32 + c];
            union { u32 u; float f; } lo, hi;
            lo.u = w << 16; hi.u = w & 0xffff0000u;
            if (sel < lim) { a0 += lo.f; a1 += hi.f; }
        }
    }
    a0 += __shfl_xor(a0, 32);
    a1 += __shfl_xor(a1, 32);
    if (l < 32) {
        float2* p = (float2*)(out + (size_t)(b * NN + n) * 64 + 2 * c);
        float2 h = *p; h.x += a0; h.y += a1; *p = h;
    }
}

// ---------------------------------------------------------------------------
extern "C" void kernel_launch(void* const* d_in, const int* in_sizes, int n_in,
                              void* d_out, int out_size, void* d_ws, size_t ws_size,
                              hipStream_t stream) {
    const float* x     = (const float*)d_in[0];
    const int*   edges = (const int*)d_in[1];
    const float* ew1   = (const float*)d_in[2];
    const float* eb1   = (const float*)d_in[3];
    const float* ew2   = (const float*)d_in[4];
    const float* eb2   = (const float*)d_in[5];
    const float* nw1   = (const float*)d_in[6];
    const float* nb1   = (const float*)d_in[7];
    const float* nw2   = (const float*)d_in[8];
    const float* nb2   = (const float*)d_in[9];
    const float* dw    = (const float*)d_in[10];
    const float* db    = (const float*)d_in[11];
    float* out = (float*)d_out;    // [BN][64]

    // Workspace layout (512B aligned)
    char* w = (char*)d_ws;
    size_t o = 0;
    auto take = [&](size_t bytes) { char* p = w + o; o = (o + bytes + 511) & ~(size_t)511; return p; };
    u16*   frag   = (u16*)  take(81920 * 2);               // 160 KB
    float* bias2  = (float*)take(128 * 4);
    int*   cursor = (int*)  take((size_t)NN * 4);          // 200 KB
    int*   off    = (int*)  take((size_t)(NN + 1) * 4);    // 200 KB
    int*   inc    = (int*)  take((size_t)2 * NE * 4);      // 4 MB
    u16*   xbf    = (u16*)  take((size_t)BN * 64 * 2);     // 12.8 MB
    u16*   edec   = (u16*)  take((size_t)NE * 64 * 2);     // 64 MB (per-batch reuse)

    // CSR build (edges batch-invariant)
    csr_zero<<<(NN + 255) / 256, 256, 0, stream>>>(cursor);
    csr_hist<<<(NE + 255) / 256, 256, 0, stream>>>(edges, cursor);
    csr_scan<<<1, 256, 0, stream>>>(cursor, off);
    csr_fill<<<(NE + 255) / 256, 256, 0, stream>>>(edges, cursor, inc);

    // Weight prep + x conversion
    swizzle_w1<<<192, 256, 0, stream>>>(ew1, nw1, frag);
    fuse_w2<<<128, 256, 0, stream>>>(ew2, nw2, dw, frag);
    fuse_bias<<<1, 64, 0, stream>>>(eb2, nb2, dw, db, bias2);
    x_to_bf16<<<(BN * 16 + 255) / 256, 256, 0, stream>>>(x, xbf);

    // Node term -> out base
    node_mlp_kernel<<<(BN + 63) / 64, 256, 0, stream>>>(xbf, nb1, bias2, frag, out);

    // Edge term per batch
    for (int b = 0; b < BB; ++b) {
        edge_emb_kernel<<<(NE + 63) / 64, 256, 0, stream>>>(xbf, edges, eb1, bias2, frag, edec, b);
        gather_kernel<<<NN / 4, 256, 0, stream>>>((const u32*)edec, off, inc, out, b);
    }
}

// Round 8
// 491.536 us; speedup vs baseline: 6.9141x; 1.2674x over previous
//
#include <hip/hip_runtime.h>
#include <hip/hip_bf16.h>

// Problem constants
#define BB   2
#define NN   50000
#define BN   100000     // B*N
#define NE   500000
#define NSB  196        // scan blocks = ceil(NN/256)

#define EPITCH 136      // ein LDS pitch (bf16 elems): 68 dwords = 4 mod 32 banks
#define XPITCH 72       // node xs pitch: 36 dwords = 4 mod 32
#define HPITCH 264      // hid LDS pitch: 132 dwords = 4 mod 32

using u16 = unsigned short;
using u32 = unsigned int;
typedef __attribute__((ext_vector_type(8))) short short8;   // 8 x bf16 (4 VGPRs)
typedef __attribute__((ext_vector_type(4))) short short4v;  // 4 x bf16 (8B)
typedef __attribute__((ext_vector_type(4))) float f32x4;    // MFMA accumulator

__device__ __forceinline__ u16 f2bf(float f) {   // RNE f32 -> bf16 (finite inputs)
    union { float f; u32 u; } w; w.f = f;
    return (u16)((w.u + 0x7fffu + ((w.u >> 16) & 1u)) >> 16);
}

// ---------------------------------------------------------------------------
// CSR build over undirected incidences (node -> incident edge ids).
// ---------------------------------------------------------------------------
__global__ __launch_bounds__(256) void csr_zero(int* __restrict__ cursor) {
    int i = blockIdx.x * 256 + threadIdx.x;
    if (i < NN) cursor[i] = 0;
}

__global__ __launch_bounds__(256) void csr_hist(const int* __restrict__ edges,
                                                int* __restrict__ cursor) {
    int e = blockIdx.x * 256 + threadIdx.x;
    if (e < NE) {
        atomicAdd(&cursor[edges[2*e]], 1);
        atomicAdd(&cursor[edges[2*e+1]], 1);
    }
}

// pass 1: per-block sums of deg
__global__ __launch_bounds__(256) void scan_pass1(const int* __restrict__ cursor,
                                                  int* __restrict__ bsum) {
    __shared__ int s[256];
    const int t = threadIdx.x;
    int i = blockIdx.x * 256 + t;
    s[t] = (i < NN) ? cursor[i] : 0;
    __syncthreads();
    for (int d = 128; d > 0; d >>= 1) {
        if (t < d) s[t] += s[t + d];
        __syncthreads();
    }
    if (t == 0) bsum[blockIdx.x] = s[0];
}

// pass 2: exclusive scan of the NSB block sums (single block)
__global__ __launch_bounds__(256) void scan_pass2(const int* __restrict__ bsum,
                                                  int* __restrict__ boff) {
    __shared__ int s[256];
    const int t = threadIdx.x;
    s[t] = (t < NSB) ? bsum[t] : 0;
    __syncthreads();
    for (int d = 1; d < 256; d <<= 1) {
        int v = (t >= d) ? s[t - d] : 0;
        __syncthreads();
        s[t] += v;
        __syncthreads();
    }
    if (t <= NSB) boff[t] = (t == 0) ? 0 : s[t - 1];
}

// pass 3: per-block inclusive scan + block offset -> off[], cursor[]
__global__ __launch_bounds__(256) void scan_pass3(int* __restrict__ cursor,
                                                  const int* __restrict__ boff,
                                                  int* __restrict__ off) {
    __shared__ int s[256];
    const int t = threadIdx.x;
    int i = blockIdx.x * 256 + t;
    int v = (i < NN) ? cursor[i] : 0;
    s[t] = v;
    __syncthreads();
    for (int d = 1; d < 256; d <<= 1) {
        int p = (t >= d) ? s[t - d] : 0;
        __syncthreads();
        s[t] += p;
        __syncthreads();
    }
    int excl = boff[blockIdx.x] + s[t] - v;
    if (i < NN) { off[i] = excl; cursor[i] = excl; }
    if (i == NN - 1) off[NN] = excl + v;
}

__global__ __launch_bounds__(256) void csr_fill(const int* __restrict__ edges,
                                                int* __restrict__ cursor,
                                                int* __restrict__ inc) {
    int e = blockIdx.x * 256 + threadIdx.x;
    if (e < NE) {
        int pu = atomicAdd(&cursor[edges[2*e]], 1);   inc[pu] = e;
        int pv = atomicAdd(&cursor[edges[2*e+1]], 1); inc[pv] = e;
    }
}

// ---------------------------------------------------------------------------
// W1 pre-swizzle: A-fragment layout for mfma_f32_16x16x32_bf16.
// Regions (u16): w1e @0 ([16][4][64][8]), w1n @32768 ([16][2][64][8]),
//                w2e' @49152 ([4][8][64][8]), w2n' @65536 ([4][8][64][8]).
// ---------------------------------------------------------------------------
__global__ __launch_bounds__(256) void swizzle_w1(
    const float* __restrict__ ew1, const float* __restrict__ nw1,
    u16* __restrict__ frag)
{
    int idx = blockIdx.x * 256 + threadIdx.x;   // 0 .. 49151
    if (idx >= 49152) return;
    const float* src; int KB, local;
    if (idx < 32768) { local = idx;         src = ew1; KB = 4; }
    else             { local = idx - 32768; src = nw1; KB = 2; }
    int j = local & 7, l = (local >> 3) & 63, rest = local >> 9;
    int kblk = rest % KB, ntile = rest / KB;
    int n = ntile * 16 + (l & 15);
    int k = kblk * 32 + ((l >> 4) << 3) + j;
    frag[idx] = f2bf(src[k * 256 + n]);
}

// Fused W2' = W2 @ dw (256x64), straight into A-frag layout.
__global__ __launch_bounds__(256) void fuse_w2(
    const float* __restrict__ ew2, const float* __restrict__ nw2,
    const float* __restrict__ dw, u16* __restrict__ frag)
{
    int idx = blockIdx.x * 256 + threadIdx.x;   // 0 .. 32767
    if (idx >= 32768) return;
    const float* src = (idx < 16384) ? ew2 : nw2;
    int local = idx & 16383;
    int j = local & 7, l = (local >> 3) & 63, rest = local >> 9;  // 0..31
    int kblk = rest & 7, ntile = rest >> 3;
    int n = ntile * 16 + (l & 15);              // 0..63
    int k = kblk * 32 + ((l >> 4) << 3) + j;    // 0..255
    float s = 0.f;
    for (int jj = 0; jj < 128; ++jj) s = fmaf(src[k * 128 + jj], dw[jj * 64 + n], s);
    frag[49152 + idx] = f2bf(s);
}

// bias2[0:64] = eb2@dw ; bias2[64:128] = nb2@dw + db
__global__ __launch_bounds__(64) void fuse_bias(
    const float* __restrict__ eb2, const float* __restrict__ nb2,
    const float* __restrict__ dw, const float* __restrict__ db,
    float* __restrict__ bias2)
{
    int d = threadIdx.x;
    float se = 0.f, sn = 0.f;
    for (int j = 0; j < 128; ++j) {
        float w = dw[j * 64 + d];
        se = fmaf(eb2[j], w, se);
        sn = fmaf(nb2[j], w, sn);
    }
    bias2[d] = se;
    bias2[64 + d] = sn + db[d];
}

// x (f32) -> xbf (bf16), once.
__global__ __launch_bounds__(256) void x_to_bf16(const float* __restrict__ x,
                                                 u16* __restrict__ xbf)
{
    int i = blockIdx.x * 256 + threadIdx.x;    // float4 groups
    if (i >= BN * 16) return;
    float4 g = ((const float4*)x)[i];
    short4v s;
    s.x = (short)f2bf(g.x); s.y = (short)f2bf(g.y);
    s.z = (short)f2bf(g.z); s.w = (short)f2bf(g.w);
    *(short4v*)(xbf + (size_t)i * 4) = s;
}

// ---------------------------------------------------------------------------
// Node MLP (dw-fused): out[r][0:64] = relu(x[r]@nw1+nb1)@(nw2@dw) + (nb2@dw+db)
// ---------------------------------------------------------------------------
__global__ __launch_bounds__(256) void node_mlp_kernel(
    const u16* __restrict__ xbf, const float* __restrict__ nb1,
    const float* __restrict__ bias2, const u16* __restrict__ frag,
    float* __restrict__ out)
{
    __shared__ u16 xs[64 * XPITCH];    // 9216 B
    __shared__ u16 hid[64 * HPITCH];   // 33792 B
    const int t = threadIdx.x;
    const int wave = t >> 6, l = t & 63, lane15 = l & 15, quad = l >> 4;
    const int r0 = blockIdx.x * 64;
    const int valid = min(64, BN - r0);

    #pragma unroll
    for (int it = 0; it < 2; ++it) {
        int i = t + it * 256;          // 0..511
        int m = i >> 3, c8 = i & 7;
        int row = min(r0 + m, BN - 1);
        uint4 q = ((const uint4*)xbf)[(size_t)row * 8 + c8];
        *(uint4*)(xs + m * XPITCH + c8 * 8) = q;
    }
    __syncthreads();

    {   // GEMM1^T, K=64
        f32x4 acc[4][4];
        #pragma unroll
        for (int i = 0; i < 4; ++i)
            #pragma unroll
            for (int mt = 0; mt < 4; ++mt) acc[i][mt] = f32x4{0.f,0.f,0.f,0.f};
        const u16* w1 = frag + 32768;    // [16][2][64][8]
        #pragma unroll
        for (int kblk = 0; kblk < 2; ++kblk) {
            short8 bf[4], af[4];
            #pragma unroll
            for (int mt = 0; mt < 4; ++mt)
                bf[mt] = *(const short8*)(xs + (mt*16 + lane15) * XPITCH + kblk*32 + quad*8);
            #pragma unroll
            for (int i = 0; i < 4; ++i)
                af[i] = *(const short8*)(w1 + (((wave*4 + i)*2 + kblk)*64 + l) * 8);
            #pragma unroll
            for (int i = 0; i < 4; ++i)
                #pragma unroll
                for (int mt = 0; mt < 4; ++mt)
                    acc[i][mt] = __builtin_amdgcn_mfma_f32_16x16x32_bf16(af[i], bf[mt], acc[i][mt], 0, 0, 0);
        }
        #pragma unroll
        for (int i = 0; i < 4; ++i) {
            int n0 = (wave*4 + i)*16 + quad*4;
            float4 bv = *(const float4*)(nb1 + n0);
            #pragma unroll
            for (int mt = 0; mt < 4; ++mt) {
                int m = mt*16 + lane15;
                short4v s;
                s.x = (short)f2bf(fmaxf(acc[i][mt][0] + bv.x, 0.f));
                s.y = (short)f2bf(fmaxf(acc[i][mt][1] + bv.y, 0.f));
                s.z = (short)f2bf(fmaxf(acc[i][mt][2] + bv.z, 0.f));
                s.w = (short)f2bf(fmaxf(acc[i][mt][3] + bv.w, 0.f));
                *(short4v*)(hid + m * HPITCH + n0) = s;
            }
        }
    }
    __syncthreads();

    {   // fused GEMM2^T: N=64, K=256 -> f32 out
        f32x4 acc[4];
        #pragma unroll
        for (int mt = 0; mt < 4; ++mt) acc[mt] = f32x4{0.f,0.f,0.f,0.f};
        const u16* w2 = frag + 65536;    // [4][8][64][8], ntile = wave
        #pragma unroll
        for (int kblk = 0; kblk < 8; ++kblk) {
            short8 bf[4], af;
            #pragma unroll
            for (int mt = 0; mt < 4; ++mt)
                bf[mt] = *(const short8*)(hid + (mt*16 + lane15) * HPITCH + kblk*32 + quad*8);
            af = *(const short8*)(w2 + ((wave*8 + kblk)*64 + l) * 8);
            #pragma unroll
            for (int mt = 0; mt < 4; ++mt)
                acc[mt] = __builtin_amdgcn_mfma_f32_16x16x32_bf16(af, bf[mt], acc[mt], 0, 0, 0);
        }
        int n0 = wave*16 + quad*4;
        float4 bv = *(const float4*)(bias2 + 64 + n0);
        #pragma unroll
        for (int mt = 0; mt < 4; ++mt) {
            int m = mt*16 + lane15;
            if (m < valid) {
                float4 o;
                o.x = acc[mt][0] + bv.x; o.y = acc[mt][1] + bv.y;
                o.z = acc[mt][2] + bv.z; o.w = acc[mt][3] + bv.w;
                *(float4*)(out + (size_t)(r0 + m) * 64 + n0) = o;
            }
        }
    }
}

// ---------------------------------------------------------------------------
// Edge MLP (dw-fused) -> edec (bf16 [BB][NE][64]). grid.y = batch.
// ---------------------------------------------------------------------------
__global__ __launch_bounds__(256) void edge_emb_kernel(
    const u16* __restrict__ xbf, const int* __restrict__ edges,
    const float* __restrict__ eb1, const float* __restrict__ bias2,
    const u16* __restrict__ frag, u16* __restrict__ edec)
{
    __shared__ u16 ein[64 * EPITCH];   // 17408 B
    __shared__ u16 hid[64 * HPITCH];   // 33792 B
    __shared__ int us[64], vs[64];
    const int t = threadIdx.x;
    const int wave = t >> 6, l = t & 63, lane15 = l & 15, quad = l >> 4;
    const int b = blockIdx.y;
    const int e0 = blockIdx.x * 64;
    const int valid = min(64, NE - e0);

    if (t < 64) {
        int e = min(e0 + t, NE - 1);
        us[t] = edges[2 * e];
        vs[t] = edges[2 * e + 1];
    }
    __syncthreads();

    #pragma unroll
    for (int it = 0; it < 4; ++it) {
        int i = t + it * 256;           // 0..1023
        int m = i >> 4, c = i & 15;
        int half = c >> 3, c8 = c & 7;
        int node = half ? vs[m] : us[m];
        uint4 q = ((const uint4*)xbf)[(size_t)(b * NN + node) * 8 + c8];
        *(uint4*)(ein + m * EPITCH + half * 64 + c8 * 8) = q;
    }
    __syncthreads();

    {   // GEMM1^T, K=128
        f32x4 acc[4][4];
        #pragma unroll
        for (int i = 0; i < 4; ++i)
            #pragma unroll
            for (int mt = 0; mt < 4; ++mt) acc[i][mt] = f32x4{0.f,0.f,0.f,0.f};
        const u16* w1 = frag;            // [16][4][64][8]
        #pragma unroll
        for (int kblk = 0; kblk < 4; ++kblk) {
            short8 bf[4], af[4];
            #pragma unroll
            for (int mt = 0; mt < 4; ++mt)
                bf[mt] = *(const short8*)(ein + (mt*16 + lane15) * EPITCH + kblk*32 + quad*8);
            #pragma unroll
            for (int i = 0; i < 4; ++i)
                af[i] = *(const short8*)(w1 + (((wave*4 + i)*4 + kblk)*64 + l) * 8);
            #pragma unroll
            for (int i = 0; i < 4; ++i)
                #pragma unroll
                for (int mt = 0; mt < 4; ++mt)
                    acc[i][mt] = __builtin_amdgcn_mfma_f32_16x16x32_bf16(af[i], bf[mt], acc[i][mt], 0, 0, 0);
        }
        #pragma unroll
        for (int i = 0; i < 4; ++i) {
            int n0 = (wave*4 + i)*16 + quad*4;
            float4 bv = *(const float4*)(eb1 + n0);
            #pragma unroll
            for (int mt = 0; mt < 4; ++mt) {
                int m = mt*16 + lane15;
                short4v s;
                s.x = (short)f2bf(fmaxf(acc[i][mt][0] + bv.x, 0.f));
                s.y = (short)f2bf(fmaxf(acc[i][mt][1] + bv.y, 0.f));
                s.z = (short)f2bf(fmaxf(acc[i][mt][2] + bv.z, 0.f));
                s.w = (short)f2bf(fmaxf(acc[i][mt][3] + bv.w, 0.f));
                *(short4v*)(hid + m * HPITCH + n0) = s;
            }
        }
    }
    __syncthreads();

    {   // fused GEMM2^T: N=64, K=256 -> bf16 edec store
        f32x4 acc[4];
        #pragma unroll
        for (int mt = 0; mt < 4; ++mt) acc[mt] = f32x4{0.f,0.f,0.f,0.f};
        const u16* w2 = frag + 49152;    // [4][8][64][8], ntile = wave
        #pragma unroll
        for (int kblk = 0; kblk < 8; ++kblk) {
            short8 bf[4], af;
            #pragma unroll
            for (int mt = 0; mt < 4; ++mt)
                bf[mt] = *(const short8*)(hid + (mt*16 + lane15) * HPITCH + kblk*32 + quad*8);
            af = *(const short8*)(w2 + ((wave*8 + kblk)*64 + l) * 8);
            #pragma unroll
            for (int mt = 0; mt < 4; ++mt)
                acc[mt] = __builtin_amdgcn_mfma_f32_16x16x32_bf16(af, bf[mt], acc[mt], 0, 0, 0);
        }
        int n0 = wave*16 + quad*4;
        float4 bv = *(const float4*)(bias2 + n0);
        #pragma unroll
        for (int mt = 0; mt < 4; ++mt) {
            int m = mt*16 + lane15;
            if (m < valid) {
                short4v s;
                s.x = (short)f2bf(acc[mt][0] + bv.x);
                s.y = (short)f2bf(acc[mt][1] + bv.y);
                s.z = (short)f2bf(acc[mt][2] + bv.z);
                s.w = (short)f2bf(acc[mt][3] + bv.w);
                *(short4v*)(edec + ((size_t)b * NE + e0 + m) * 64 + n0) = s;
            }
        }
    }
}

// ---------------------------------------------------------------------------
// Gather: out[b][n][:] += sum of edec[b] rows of incident edges.
// One wave per node; 2 edges per iteration (32 lanes each). grid.y = batch.
// ---------------------------------------------------------------------------
__global__ __launch_bounds__(256) void gather_kernel(
    const u32* __restrict__ edec32, const int* __restrict__ off,
    const int* __restrict__ inc, float* __restrict__ out)
{
    const int t = threadIdx.x, wave = t >> 6, l = t & 63;
    const int b = blockIdx.y;
    const int n = blockIdx.x * 4 + wave;
    const int base = off[n], cnt = off[n + 1] - base;
    if (cnt == 0) return;                   // wave-uniform
    const int half = l >> 5, c = l & 31;
    const u32* eb = edec32 + (size_t)b * NE * 32;
    float a0 = 0.f, a1 = 0.f;
    for (int j0 = 0; j0 < cnt; j0 += 64) {
        int ev = inc[min(base + j0 + l, 2 * NE - 1)];
        int lim = min(64, cnt - j0);
        for (int i = 0; i < lim; i += 2) {
            int sel = i + half;
            int e = __shfl(ev, sel);
            u32 w = eb[(size_t)e * 32 + c];
            union { u32 u; float f; } lo, hi;
            lo.u = w << 16; hi.u = w & 0xffff0000u;
            if (sel < lim) { a0 += lo.f; a1 += hi.f; }
        }
    }
    a0 += __shfl_xor(a0, 32);
    a1 += __shfl_xor(a1, 32);
    if (l < 32) {
        float2* p = (float2*)(out + (size_t)(b * NN + n) * 64 + 2 * c);
        float2 h = *p; h.x += a0; h.y += a1; *p = h;
    }
}

// ---------------------------------------------------------------------------
extern "C" void kernel_launch(void* const* d_in, const int* in_sizes, int n_in,
                              void* d_out, int out_size, void* d_ws, size_t ws_size,
                              hipStream_t stream) {
    const float* x     = (const float*)d_in[0];
    const int*   edges = (const int*)d_in[1];
    const float* ew1   = (const float*)d_in[2];
    const float* eb1   = (const float*)d_in[3];
    const float* ew2   = (const float*)d_in[4];
    const float* eb2   = (const float*)d_in[5];
    const float* nw1   = (const float*)d_in[6];
    const float* nb1   = (const float*)d_in[7];
    const float* nw2   = (const float*)d_in[8];
    const float* nb2   = (const float*)d_in[9];
    const float* dw    = (const float*)d_in[10];
    const float* db    = (const float*)d_in[11];
    float* out = (float*)d_out;    // [BN][64]

    // Workspace layout (512B aligned)
    char* w = (char*)d_ws;
    size_t o = 0;
    auto take = [&](size_t bytes) { char* p = w + o; o = (o + bytes + 511) & ~(size_t)511; return p; };
    u16*   frag   = (u16*)  take(81920 * 2);               // 160 KB
    float* bias2  = (float*)take(128 * 4);
    int*   cursor = (int*)  take((size_t)NN * 4);          // 200 KB
    int*   off    = (int*)  take((size_t)(NN + 1) * 4);    // 200 KB
    int*   bsum   = (int*)  take((size_t)(NSB + 1) * 4);
    int*   boff   = (int*)  take((size_t)(NSB + 1) * 4);
    int*   inc    = (int*)  take((size_t)2 * NE * 4);      // 4 MB
    u16*   xbf    = (u16*)  take((size_t)BN * 64 * 2);     // 12.8 MB
    u16*   edec   = (u16*)  take((size_t)BB * NE * 64 * 2);// 128 MB

    // CSR build (edges batch-invariant)
    csr_zero<<<NSB, 256, 0, stream>>>(cursor);
    csr_hist<<<(NE + 255) / 256, 256, 0, stream>>>(edges, cursor);
    scan_pass1<<<NSB, 256, 0, stream>>>(cursor, bsum);
    scan_pass2<<<1, 256, 0, stream>>>(bsum, boff);
    scan_pass3<<<NSB, 256, 0, stream>>>(cursor, boff, off);
    csr_fill<<<(NE + 255) / 256, 256, 0, stream>>>(edges, cursor, inc);

    // Weight prep + x conversion
    swizzle_w1<<<192, 256, 0, stream>>>(ew1, nw1, frag);
    fuse_w2<<<128, 256, 0, stream>>>(ew2, nw2, dw, frag);
    fuse_bias<<<1, 64, 0, stream>>>(eb2, nb2, dw, db, bias2);
    x_to_bf16<<<(BN * 16 + 255) / 256, 256, 0, stream>>>(x, xbf);

    // Node term -> out base
    node_mlp_kernel<<<(BN + 63) / 64, 256, 0, stream>>>(xbf, nb1, bias2, frag, out);

    // Edge term, both batches at once
    edge_emb_kernel<<<dim3((NE + 63) / 64, BB), 256, 0, stream>>>(xbf, edges, eb1, bias2, frag, edec);
    gather_kernel<<<dim3(NN / 4, BB), 256, 0, stream>>>((const u32*)edec, off, inc, out);
}

// Round 9
// 465.376 us; speedup vs baseline: 7.3028x; 1.0562x over previous
//
#include <hip/hip_runtime.h>
#include <hip/hip_bf16.h>

// Problem constants
#define BB   2
#define NN   50000
#define BN   100000     // B*N
#define NE   500000
#define NSB  196        // scan blocks = ceil(NN/256)

#define EPITCH 136      // ein LDS pitch (bf16): 272 B, 16B aligned
#define XPITCH 72       // node xs pitch: 144 B
#define HPITCH 264      // hid LDS pitch: 528 B
#define RPITCH 72       // erow pitch: 144 B, 16B aligned

using u16 = unsigned short;
using u32 = unsigned int;
typedef __attribute__((ext_vector_type(8))) short short8;   // 8 x bf16 (4 VGPRs)
typedef __attribute__((ext_vector_type(4))) short short4v;  // 4 x bf16 (8B)
typedef __attribute__((ext_vector_type(4))) float f32x4;    // MFMA accumulator

__device__ __forceinline__ u16 f2bf(float f) {   // RNE f32 -> bf16 (finite inputs)
    union { float f; u32 u; } w; w.f = f;
    return (u16)((w.u + 0x7fffu + ((w.u >> 16) & 1u)) >> 16);
}

// ---------------------------------------------------------------------------
// CSR build: node -> contiguous slots [off[n], off[n+1]) ; pos[i] = slot of
// incidence i (i = 2e for u, 2e+1 for v).
// ---------------------------------------------------------------------------
__global__ __launch_bounds__(256) void csr_zero(int* __restrict__ cursor) {
    int i = blockIdx.x * 256 + threadIdx.x;
    if (i < NN) cursor[i] = 0;
}

__global__ __launch_bounds__(256) void csr_hist(const int* __restrict__ edges,
                                                int* __restrict__ cursor) {
    int e = blockIdx.x * 256 + threadIdx.x;
    if (e < NE) {
        atomicAdd(&cursor[edges[2*e]], 1);
        atomicAdd(&cursor[edges[2*e+1]], 1);
    }
}

__global__ __launch_bounds__(256) void scan_pass1(const int* __restrict__ cursor,
                                                  int* __restrict__ bsum) {
    __shared__ int s[256];
    const int t = threadIdx.x;
    int i = blockIdx.x * 256 + t;
    s[t] = (i < NN) ? cursor[i] : 0;
    __syncthreads();
    for (int d = 128; d > 0; d >>= 1) {
        if (t < d) s[t] += s[t + d];
        __syncthreads();
    }
    if (t == 0) bsum[blockIdx.x] = s[0];
}

__global__ __launch_bounds__(256) void scan_pass2(const int* __restrict__ bsum,
                                                  int* __restrict__ boff) {
    __shared__ int s[256];
    const int t = threadIdx.x;
    s[t] = (t < NSB) ? bsum[t] : 0;
    __syncthreads();
    for (int d = 1; d < 256; d <<= 1) {
        int v = (t >= d) ? s[t - d] : 0;
        __syncthreads();
        s[t] += v;
        __syncthreads();
    }
    if (t <= NSB) boff[t] = (t == 0) ? 0 : s[t - 1];
}

__global__ __launch_bounds__(256) void scan_pass3(int* __restrict__ cursor,
                                                  const int* __restrict__ boff,
                                                  int* __restrict__ off) {
    __shared__ int s[256];
    const int t = threadIdx.x;
    int i = blockIdx.x * 256 + t;
    int v = (i < NN) ? cursor[i] : 0;
    s[t] = v;
    __syncthreads();
    for (int d = 1; d < 256; d <<= 1) {
        int p = (t >= d) ? s[t - d] : 0;
        __syncthreads();
        s[t] += p;
        __syncthreads();
    }
    int excl = boff[blockIdx.x] + s[t] - v;
    if (i < NN) { off[i] = excl; cursor[i] = excl; }
    if (i == NN - 1) off[NN] = excl + v;
}

__global__ __launch_bounds__(256) void csr_fill(const int* __restrict__ edges,
                                                int* __restrict__ cursor,
                                                int* __restrict__ pos) {
    int e = blockIdx.x * 256 + threadIdx.x;
    if (e < NE) {
        pos[2*e]     = atomicAdd(&cursor[edges[2*e]], 1);
        pos[2*e + 1] = atomicAdd(&cursor[edges[2*e+1]], 1);
    }
}

// ---------------------------------------------------------------------------
// W1 pre-swizzle: A-fragment layout for mfma_f32_16x16x32_bf16.
// Regions (u16): w1e @0 ([16][4][64][8]), w1n @32768 ([16][2][64][8]),
//                w2e' @49152 ([4][8][64][8]), w2n' @65536 ([4][8][64][8]).
// ---------------------------------------------------------------------------
__global__ __launch_bounds__(256) void swizzle_w1(
    const float* __restrict__ ew1, const float* __restrict__ nw1,
    u16* __restrict__ frag)
{
    int idx = blockIdx.x * 256 + threadIdx.x;   // 0 .. 49151
    if (idx >= 49152) return;
    const float* src; int KB, local;
    if (idx < 32768) { local = idx;         src = ew1; KB = 4; }
    else             { local = idx - 32768; src = nw1; KB = 2; }
    int j = local & 7, l = (local >> 3) & 63, rest = local >> 9;
    int kblk = rest % KB, ntile = rest / KB;
    int n = ntile * 16 + (l & 15);
    int k = kblk * 32 + ((l >> 4) << 3) + j;
    frag[idx] = f2bf(src[k * 256 + n]);
}

__global__ __launch_bounds__(256) void fuse_w2(
    const float* __restrict__ ew2, const float* __restrict__ nw2,
    const float* __restrict__ dw, u16* __restrict__ frag)
{
    int idx = blockIdx.x * 256 + threadIdx.x;   // 0 .. 32767
    if (idx >= 32768) return;
    const float* src = (idx < 16384) ? ew2 : nw2;
    int local = idx & 16383;
    int j = local & 7, l = (local >> 3) & 63, rest = local >> 9;  // 0..31
    int kblk = rest & 7, ntile = rest >> 3;
    int n = ntile * 16 + (l & 15);              // 0..63
    int k = kblk * 32 + ((l >> 4) << 3) + j;    // 0..255
    float s = 0.f;
    for (int jj = 0; jj < 128; ++jj) s = fmaf(src[k * 128 + jj], dw[jj * 64 + n], s);
    frag[49152 + idx] = f2bf(s);
}

__global__ __launch_bounds__(64) void fuse_bias(
    const float* __restrict__ eb2, const float* __restrict__ nb2,
    const float* __restrict__ dw, const float* __restrict__ db,
    float* __restrict__ bias2)
{
    int d = threadIdx.x;
    float se = 0.f, sn = 0.f;
    for (int j = 0; j < 128; ++j) {
        float w = dw[j * 64 + d];
        se = fmaf(eb2[j], w, se);
        sn = fmaf(nb2[j], w, sn);
    }
    bias2[d] = se;
    bias2[64 + d] = sn + db[d];
}

__global__ __launch_bounds__(256) void x_to_bf16(const float* __restrict__ x,
                                                 u16* __restrict__ xbf)
{
    int i = blockIdx.x * 256 + threadIdx.x;    // float4 groups
    if (i >= BN * 16) return;
    float4 g = ((const float4*)x)[i];
    short4v s;
    s.x = (short)f2bf(g.x); s.y = (short)f2bf(g.y);
    s.z = (short)f2bf(g.z); s.w = (short)f2bf(g.w);
    *(short4v*)(xbf + (size_t)i * 4) = s;
}

// ---------------------------------------------------------------------------
// Node MLP (dw-fused): out[r][0:64] = relu(x[r]@nw1+nb1)@(nw2@dw) + (nb2@dw+db)
// ---------------------------------------------------------------------------
__global__ __launch_bounds__(256) void node_mlp_kernel(
    const u16* __restrict__ xbf, const float* __restrict__ nb1,
    const float* __restrict__ bias2, const u16* __restrict__ frag,
    float* __restrict__ out)
{
    __shared__ u16 xs[64 * XPITCH];    // 9216 B
    __shared__ u16 hid[64 * HPITCH];   // 33792 B
    const int t = threadIdx.x;
    const int wave = t >> 6, l = t & 63, lane15 = l & 15, quad = l >> 4;
    const int r0 = blockIdx.x * 64;
    const int valid = min(64, BN - r0);

    #pragma unroll
    for (int it = 0; it < 2; ++it) {
        int i = t + it * 256;          // 0..511
        int m = i >> 3, c8 = i & 7;
        int row = min(r0 + m, BN - 1);
        uint4 q = ((const uint4*)xbf)[(size_t)row * 8 + c8];
        *(uint4*)(xs + m * XPITCH + c8 * 8) = q;
    }
    __syncthreads();

    {   // GEMM1^T, K=64
        f32x4 acc[4][4];
        #pragma unroll
        for (int i = 0; i < 4; ++i)
            #pragma unroll
            for (int mt = 0; mt < 4; ++mt) acc[i][mt] = f32x4{0.f,0.f,0.f,0.f};
        const u16* w1 = frag + 32768;    // [16][2][64][8]
        #pragma unroll
        for (int kblk = 0; kblk < 2; ++kblk) {
            short8 bf[4], af[4];
            #pragma unroll
            for (int mt = 0; mt < 4; ++mt)
                bf[mt] = *(const short8*)(xs + (mt*16 + lane15) * XPITCH + kblk*32 + quad*8);
            #pragma unroll
            for (int i = 0; i < 4; ++i)
                af[i] = *(const short8*)(w1 + (((wave*4 + i)*2 + kblk)*64 + l) * 8);
            #pragma unroll
            for (int i = 0; i < 4; ++i)
                #pragma unroll
                for (int mt = 0; mt < 4; ++mt)
                    acc[i][mt] = __builtin_amdgcn_mfma_f32_16x16x32_bf16(af[i], bf[mt], acc[i][mt], 0, 0, 0);
        }
        #pragma unroll
        for (int i = 0; i < 4; ++i) {
            int n0 = (wave*4 + i)*16 + quad*4;
            float4 bv = *(const float4*)(nb1 + n0);
            #pragma unroll
            for (int mt = 0; mt < 4; ++mt) {
                int m = mt*16 + lane15;
                short4v s;
                s.x = (short)f2bf(fmaxf(acc[i][mt][0] + bv.x, 0.f));
                s.y = (short)f2bf(fmaxf(acc[i][mt][1] + bv.y, 0.f));
                s.z = (short)f2bf(fmaxf(acc[i][mt][2] + bv.z, 0.f));
                s.w = (short)f2bf(fmaxf(acc[i][mt][3] + bv.w, 0.f));
                *(short4v*)(hid + m * HPITCH + n0) = s;
            }
        }
    }
    __syncthreads();

    {   // fused GEMM2^T: N=64, K=256 -> f32 out
        f32x4 acc[4];
        #pragma unroll
        for (int mt = 0; mt < 4; ++mt) acc[mt] = f32x4{0.f,0.f,0.f,0.f};
        const u16* w2 = frag + 65536;    // [4][8][64][8], ntile = wave
        #pragma unroll
        for (int kblk = 0; kblk < 8; ++kblk) {
            short8 bf[4], af;
            #pragma unroll
            for (int mt = 0; mt < 4; ++mt)
                bf[mt] = *(const short8*)(hid + (mt*16 + lane15) * HPITCH + kblk*32 + quad*8);
            af = *(const short8*)(w2 + ((wave*8 + kblk)*64 + l) * 8);
            #pragma unroll
            for (int mt = 0; mt < 4; ++mt)
                acc[mt] = __builtin_amdgcn_mfma_f32_16x16x32_bf16(af, bf[mt], acc[mt], 0, 0, 0);
        }
        int n0 = wave*16 + quad*4;
        float4 bv = *(const float4*)(bias2 + 64 + n0);
        #pragma unroll
        for (int mt = 0; mt < 4; ++mt) {
            int m = mt*16 + lane15;
            if (m < valid) {
                float4 o;
                o.x = acc[mt][0] + bv.x; o.y = acc[mt][1] + bv.y;
                o.z = acc[mt][2] + bv.z; o.w = acc[mt][3] + bv.w;
                *(float4*)(out + (size_t)(r0 + m) * 64 + n0) = o;
            }
        }
    }
}

// ---------------------------------------------------------------------------
// Edge MLP (dw-fused) -> perm rows: each edge's 64-col bf16 row written to
// both CSR slots pos[2e], pos[2e+1]. Full 128-B aligned line writes.
// ---------------------------------------------------------------------------
__global__ __launch_bounds__(256) void edge_emb_kernel(
    const u16* __restrict__ xbf, const int* __restrict__ edges,
    const float* __restrict__ eb1, const float* __restrict__ bias2,
    const u16* __restrict__ frag, const int* __restrict__ pos,
    u16* __restrict__ perm, int b)
{
    __shared__ u16 ein[64 * EPITCH];   // 17408 B; reused as erow (64*RPITCH*2 = 9216 B)
    __shared__ u16 hid[64 * HPITCH];   // 33792 B
    __shared__ int us[64], vs[64], ps[64], qs[64];
    const int t = threadIdx.x;
    const int wave = t >> 6, l = t & 63, lane15 = l & 15, quad = l >> 4;
    const int e0 = blockIdx.x * 64;
    const int valid = min(64, NE - e0);

    if (t < 64) {
        int e = min(e0 + t, NE - 1);
        us[t] = edges[2 * e];
        vs[t] = edges[2 * e + 1];
        ps[t] = pos[2 * e];
        qs[t] = pos[2 * e + 1];
    }
    __syncthreads();

    #pragma unroll
    for (int it = 0; it < 4; ++it) {
        int i = t + it * 256;           // 0..1023
        int m = i >> 4, c = i & 15;
        int half = c >> 3, c8 = c & 7;
        int node = half ? vs[m] : us[m];
        uint4 q = ((const uint4*)xbf)[(size_t)(b * NN + node) * 8 + c8];
        *(uint4*)(ein + m * EPITCH + half * 64 + c8 * 8) = q;
    }
    __syncthreads();

    {   // GEMM1^T, K=128
        f32x4 acc[4][4];
        #pragma unroll
        for (int i = 0; i < 4; ++i)
            #pragma unroll
            for (int mt = 0; mt < 4; ++mt) acc[i][mt] = f32x4{0.f,0.f,0.f,0.f};
        const u16* w1 = frag;            // [16][4][64][8]
        #pragma unroll
        for (int kblk = 0; kblk < 4; ++kblk) {
            short8 bf[4], af[4];
            #pragma unroll
            for (int mt = 0; mt < 4; ++mt)
                bf[mt] = *(const short8*)(ein + (mt*16 + lane15) * EPITCH + kblk*32 + quad*8);
            #pragma unroll
            for (int i = 0; i < 4; ++i)
                af[i] = *(const short8*)(w1 + (((wave*4 + i)*4 + kblk)*64 + l) * 8);
            #pragma unroll
            for (int i = 0; i < 4; ++i)
                #pragma unroll
                for (int mt = 0; mt < 4; ++mt)
                    acc[i][mt] = __builtin_amdgcn_mfma_f32_16x16x32_bf16(af[i], bf[mt], acc[i][mt], 0, 0, 0);
        }
        #pragma unroll
        for (int i = 0; i < 4; ++i) {
            int n0 = (wave*4 + i)*16 + quad*4;
            float4 bv = *(const float4*)(eb1 + n0);
            #pragma unroll
            for (int mt = 0; mt < 4; ++mt) {
                int m = mt*16 + lane15;
                short4v s;
                s.x = (short)f2bf(fmaxf(acc[i][mt][0] + bv.x, 0.f));
                s.y = (short)f2bf(fmaxf(acc[i][mt][1] + bv.y, 0.f));
                s.z = (short)f2bf(fmaxf(acc[i][mt][2] + bv.z, 0.f));
                s.w = (short)f2bf(fmaxf(acc[i][mt][3] + bv.w, 0.f));
                *(short4v*)(hid + m * HPITCH + n0) = s;
            }
        }
    }
    __syncthreads();   // hid ready; ein no longer read -> reusable as erow

    {   // fused GEMM2^T: N=64, K=256 -> assemble rows in LDS
        f32x4 acc[4];
        #pragma unroll
        for (int mt = 0; mt < 4; ++mt) acc[mt] = f32x4{0.f,0.f,0.f,0.f};
        const u16* w2 = frag + 49152;    // [4][8][64][8], ntile = wave
        #pragma unroll
        for (int kblk = 0; kblk < 8; ++kblk) {
            short8 bf[4], af;
            #pragma unroll
            for (int mt = 0; mt < 4; ++mt)
                bf[mt] = *(const short8*)(hid + (mt*16 + lane15) * HPITCH + kblk*32 + quad*8);
            af = *(const short8*)(w2 + ((wave*8 + kblk)*64 + l) * 8);
            #pragma unroll
            for (int mt = 0; mt < 4; ++mt)
                acc[mt] = __builtin_amdgcn_mfma_f32_16x16x32_bf16(af, bf[mt], acc[mt], 0, 0, 0);
        }
        int n0 = wave*16 + quad*4;
        float4 bv = *(const float4*)(bias2 + n0);
        #pragma unroll
        for (int mt = 0; mt < 4; ++mt) {
            int m = mt*16 + lane15;
            short4v s;
            s.x = (short)f2bf(acc[mt][0] + bv.x);
            s.y = (short)f2bf(acc[mt][1] + bv.y);
            s.z = (short)f2bf(acc[mt][2] + bv.z);
            s.w = (short)f2bf(acc[mt][3] + bv.w);
            *(short4v*)(ein + m * RPITCH + n0) = s;   // erow aliases ein
        }
    }
    __syncthreads();

    // store each row to both CSR slots: 64 edges x 2 dests x 8 uint4
    #pragma unroll
    for (int it = 0; it < 4; ++it) {
        int i = t + it * 256;          // 0..1023
        int dest = i >> 3, c8 = i & 7;
        int m = dest >> 1;
        if (m < valid) {
            int p = (dest & 1) ? qs[m] : ps[m];
            ((uint4*)(perm + (size_t)p * 64))[c8] = *(const uint4*)(ein + m * RPITCH + c8 * 8);
        }
    }
}

// ---------------------------------------------------------------------------
// Gather (streaming): out[b][n][:] += sum of perm rows off[n]..off[n+1]-1.
// One wave per node, 4 rows (512 B) per iteration, fully coalesced.
// ---------------------------------------------------------------------------
__global__ __launch_bounds__(256) void gather_kernel(
    const u32* __restrict__ perm32, const int* __restrict__ off,
    float* __restrict__ out, int b)
{
    const int t = threadIdx.x, wave = t >> 6, l = t & 63;
    const int n = blockIdx.x * 4 + wave;
    const int base = off[n], cnt = off[n + 1] - base;
    if (cnt == 0) return;                   // wave-uniform
    const int slot = l >> 4, c8h = l & 15;  // row-in-group, 8B col
    float a0 = 0.f, a1 = 0.f, a2 = 0.f, a3 = 0.f;
    for (int j0 = 0; j0 < cnt; j0 += 4) {
        int j = j0 + slot;
        size_t r = (size_t)(base + min(j, cnt - 1));
        const u32* rp = perm32 + r * 32 + 2 * c8h;
        u32 w0 = rp[0], w1 = rp[1];
        if (j < cnt) {
            union { u32 u; float f; } x0, x1, x2, x3;
            x0.u = w0 << 16; x1.u = w0 & 0xffff0000u;
            x2.u = w1 << 16; x3.u = w1 & 0xffff0000u;
            a0 += x0.f; a1 += x1.f; a2 += x2.f; a3 += x3.f;
        }
    }
    a0 += __shfl_xor(a0, 16); a1 += __shfl_xor(a1, 16);
    a2 += __shfl_xor(a2, 16); a3 += __shfl_xor(a3, 16);
    a0 += __shfl_xor(a0, 32); a1 += __shfl_xor(a1, 32);
    a2 += __shfl_xor(a2, 32); a3 += __shfl_xor(a3, 32);
    if (l < 16) {
        float4* p = (float4*)(out + (size_t)(b * NN + n) * 64 + 4 * l);
        float4 h = *p;
        h.x += a0; h.y += a1; h.z += a2; h.w += a3;
        *p = h;
    }
}

// ---------------------------------------------------------------------------
extern "C" void kernel_launch(void* const* d_in, const int* in_sizes, int n_in,
                              void* d_out, int out_size, void* d_ws, size_t ws_size,
                              hipStream_t stream) {
    const float* x     = (const float*)d_in[0];
    const int*   edges = (const int*)d_in[1];
    const float* ew1   = (const float*)d_in[2];
    const float* eb1   = (const float*)d_in[3];
    const float* ew2   = (const float*)d_in[4];
    const float* eb2   = (const float*)d_in[5];
    const float* nw1   = (const float*)d_in[6];
    const float* nb1   = (const float*)d_in[7];
    const float* nw2   = (const float*)d_in[8];
    const float* nb2   = (const float*)d_in[9];
    const float* dw    = (const float*)d_in[10];
    const float* db    = (const float*)d_in[11];
    float* out = (float*)d_out;    // [BN][64]

    // Workspace layout (512B aligned); peak ~146 MB (<= 196 MB proven in R6)
    char* w = (char*)d_ws;
    size_t o = 0;
    auto take = [&](size_t bytes) { char* p = w + o; o = (o + bytes + 511) & ~(size_t)511; return p; };
    u16*   frag   = (u16*)  take(81920 * 2);               // 160 KB
    float* bias2  = (float*)take(128 * 4);
    int*   cursor = (int*)  take((size_t)NN * 4);          // 200 KB
    int*   off    = (int*)  take((size_t)(NN + 1) * 4);    // 200 KB
    int*   bsum   = (int*)  take((size_t)(NSB + 1) * 4);
    int*   boff   = (int*)  take((size_t)(NSB + 1) * 4);
    int*   pos    = (int*)  take((size_t)2 * NE * 4);      // 4 MB
    u16*   xbf    = (u16*)  take((size_t)BN * 64 * 2);     // 12.8 MB
    u16*   perm   = (u16*)  take((size_t)2 * NE * 64 * 2); // 128 MB (per-batch reuse)

    // CSR build (edges batch-invariant)
    csr_zero<<<NSB, 256, 0, stream>>>(cursor);
    csr_hist<<<(NE + 255) / 256, 256, 0, stream>>>(edges, cursor);
    scan_pass1<<<NSB, 256, 0, stream>>>(cursor, bsum);
    scan_pass2<<<1, 256, 0, stream>>>(bsum, boff);
    scan_pass3<<<NSB, 256, 0, stream>>>(cursor, boff, off);
    csr_fill<<<(NE + 255) / 256, 256, 0, stream>>>(edges, cursor, pos);

    // Weight prep + x conversion
    swizzle_w1<<<192, 256, 0, stream>>>(ew1, nw1, frag);
    fuse_w2<<<128, 256, 0, stream>>>(ew2, nw2, dw, frag);
    fuse_bias<<<1, 64, 0, stream>>>(eb2, nb2, dw, db, bias2);
    x_to_bf16<<<(BN * 16 + 255) / 256, 256, 0, stream>>>(x, xbf);

    // Node term -> out base
    node_mlp_kernel<<<(BN + 63) / 64, 256, 0, stream>>>(xbf, nb1, bias2, frag, out);

    // Edge term per batch: MLP -> CSR-permuted rows -> streaming segmented sum
    for (int b = 0; b < BB; ++b) {
        edge_emb_kernel<<<(NE + 63) / 64, 256, 0, stream>>>(xbf, edges, eb1, bias2, frag, pos, perm, b);
        gather_kernel<<<NN / 4, 256, 0, stream>>>((const u32*)perm, off, out, b);
    }
}

// Round 10
// 452.870 us; speedup vs baseline: 7.5045x; 1.0276x over previous
//
#include <hip/hip_runtime.h>
#include <hip/hip_bf16.h>

// Problem constants
#define BB   2
#define NN   50000
#define BN   100000     // B*N
#define NE   500000
#define NSB  196        // scan blocks = ceil(NN/256)

#define EPITCH 136      // ein LDS pitch (bf16): 272 B, 16B aligned, bank-stride 4
#define XPITCH 72       // node xs pitch: 144 B
#define HPITCH 264      // hid LDS pitch: 528 B
#define RPITCH 72       // erow pitch: 144 B

using u16 = unsigned short;
using u32 = unsigned int;
typedef __attribute__((ext_vector_type(8))) short short8;   // 8 x bf16 (4 VGPRs)
typedef __attribute__((ext_vector_type(4))) short short4v;  // 4 x bf16 (8B)
typedef __attribute__((ext_vector_type(4))) float f32x4;    // MFMA accumulator

__device__ __forceinline__ u16 f2bf(float f) {   // RNE f32 -> bf16 (finite inputs)
    union { float f; u32 u; } w; w.f = f;
    return (u16)((w.u + 0x7fffu + ((w.u >> 16) & 1u)) >> 16);
}

#if defined(__has_builtin)
#if __has_builtin(__builtin_amdgcn_cvt_pk_bf16_f32)
#define HAVE_CVTPK 1
#endif
#endif

// pack two f32 -> packed bf16x2 (lo in low 16, hi in high 16), RNE
__device__ __forceinline__ u32 pack_bf(float lo, float hi) {
#ifdef HAVE_CVTPK
    auto r = __builtin_amdgcn_cvt_pk_bf16_f32(lo, hi);
    u32 out; __builtin_memcpy(&out, &r, sizeof(out));
    return out;
#else
    return ((u32)f2bf(hi) << 16) | (u32)f2bf(lo);
#endif
}

// ---------------------------------------------------------------------------
// CSR build: node -> contiguous slots [off[n], off[n+1]) ; pos[i] = slot of
// incidence i (i = 2e for u, 2e+1 for v).
// ---------------------------------------------------------------------------
__global__ __launch_bounds__(256) void csr_zero(int* __restrict__ cursor) {
    int i = blockIdx.x * 256 + threadIdx.x;
    if (i < NN) cursor[i] = 0;
}

__global__ __launch_bounds__(256) void csr_hist(const int* __restrict__ edges,
                                                int* __restrict__ cursor) {
    int e = blockIdx.x * 256 + threadIdx.x;
    if (e < NE) {
        atomicAdd(&cursor[edges[2*e]], 1);
        atomicAdd(&cursor[edges[2*e+1]], 1);
    }
}

__global__ __launch_bounds__(256) void scan_pass1(const int* __restrict__ cursor,
                                                  int* __restrict__ bsum) {
    __shared__ int s[256];
    const int t = threadIdx.x;
    int i = blockIdx.x * 256 + t;
    s[t] = (i < NN) ? cursor[i] : 0;
    __syncthreads();
    for (int d = 128; d > 0; d >>= 1) {
        if (t < d) s[t] += s[t + d];
        __syncthreads();
    }
    if (t == 0) bsum[blockIdx.x] = s[0];
}

__global__ __launch_bounds__(256) void scan_pass2(const int* __restrict__ bsum,
                                                  int* __restrict__ boff) {
    __shared__ int s[256];
    const int t = threadIdx.x;
    s[t] = (t < NSB) ? bsum[t] : 0;
    __syncthreads();
    for (int d = 1; d < 256; d <<= 1) {
        int v = (t >= d) ? s[t - d] : 0;
        __syncthreads();
        s[t] += v;
        __syncthreads();
    }
    if (t <= NSB) boff[t] = (t == 0) ? 0 : s[t - 1];
}

__global__ __launch_bounds__(256) void scan_pass3(int* __restrict__ cursor,
                                                  const int* __restrict__ boff,
                                                  int* __restrict__ off) {
    __shared__ int s[256];
    const int t = threadIdx.x;
    int i = blockIdx.x * 256 + t;
    int v = (i < NN) ? cursor[i] : 0;
    s[t] = v;
    __syncthreads();
    for (int d = 1; d < 256; d <<= 1) {
        int p = (t >= d) ? s[t - d] : 0;
        __syncthreads();
        s[t] += p;
        __syncthreads();
    }
    int excl = boff[blockIdx.x] + s[t] - v;
    if (i < NN) { off[i] = excl; cursor[i] = excl; }
    if (i == NN - 1) off[NN] = excl + v;
}

__global__ __launch_bounds__(256) void csr_fill(const int* __restrict__ edges,
                                                int* __restrict__ cursor,
                                                int* __restrict__ pos) {
    int e = blockIdx.x * 256 + threadIdx.x;
    if (e < NE) {
        pos[2*e]     = atomicAdd(&cursor[edges[2*e]], 1);
        pos[2*e + 1] = atomicAdd(&cursor[edges[2*e+1]], 1);
    }
}

// ---------------------------------------------------------------------------
// W1 pre-swizzle: A-fragment layout for mfma_f32_16x16x32_bf16.
// Regions (u16): w1e @0 ([16][4][64][8]), w1n @32768 ([16][2][64][8]),
//                w2e' @49152 ([4][8][64][8]), w2n' @65536 ([4][8][64][8]).
// ---------------------------------------------------------------------------
__global__ __launch_bounds__(256) void swizzle_w1(
    const float* __restrict__ ew1, const float* __restrict__ nw1,
    u16* __restrict__ frag)
{
    int idx = blockIdx.x * 256 + threadIdx.x;   // 0 .. 49151
    if (idx >= 49152) return;
    const float* src; int KB, local;
    if (idx < 32768) { local = idx;         src = ew1; KB = 4; }
    else             { local = idx - 32768; src = nw1; KB = 2; }
    int j = local & 7, l = (local >> 3) & 63, rest = local >> 9;
    int kblk = rest % KB, ntile = rest / KB;
    int n = ntile * 16 + (l & 15);
    int k = kblk * 32 + ((l >> 4) << 3) + j;
    frag[idx] = f2bf(src[k * 256 + n]);
}

__global__ __launch_bounds__(256) void fuse_w2(
    const float* __restrict__ ew2, const float* __restrict__ nw2,
    const float* __restrict__ dw, u16* __restrict__ frag)
{
    int idx = blockIdx.x * 256 + threadIdx.x;   // 0 .. 32767
    if (idx >= 32768) return;
    const float* src = (idx < 16384) ? ew2 : nw2;
    int local = idx & 16383;
    int j = local & 7, l = (local >> 3) & 63, rest = local >> 9;  // 0..31
    int kblk = rest & 7, ntile = rest >> 3;
    int n = ntile * 16 + (l & 15);              // 0..63
    int k = kblk * 32 + ((l >> 4) << 3) + j;    // 0..255
    float s = 0.f;
    for (int jj = 0; jj < 128; ++jj) s = fmaf(src[k * 128 + jj], dw[jj * 64 + n], s);
    frag[49152 + idx] = f2bf(s);
}

// bias2[0:64] = eb2@dw ; bias2[64:128] = nb2@dw + db   (2 waves)
__global__ __launch_bounds__(128) void fuse_bias(
    const float* __restrict__ eb2, const float* __restrict__ nb2,
    const float* __restrict__ dw, const float* __restrict__ db,
    float* __restrict__ bias2)
{
    int t = threadIdx.x;           // 0..127
    int d = t & 63;
    const float* bsrc = (t >= 64) ? nb2 : eb2;   // wave-uniform select
    float s = 0.f;
    #pragma unroll 4
    for (int j = 0; j < 128; ++j) s = fmaf(bsrc[j], dw[j * 64 + d], s);
    if (t >= 64) bias2[64 + d] = s + db[d];
    else         bias2[d] = s;
}

// ---------------------------------------------------------------------------
// Node MLP (dw-fused) + x f32->bf16 conversion (writes xbf for edge kernel):
// out[r][0:64] = relu(x[r]@nw1+nb1)@(nw2@dw) + (nb2@dw+db)
// ---------------------------------------------------------------------------
__global__ __launch_bounds__(256) void node_mlp_kernel(
    const float* __restrict__ x, const float* __restrict__ nb1,
    const float* __restrict__ bias2, const u16* __restrict__ frag,
    u16* __restrict__ xbf, float* __restrict__ out)
{
    __shared__ u16 xs[64 * XPITCH];    // 9216 B
    __shared__ u16 hid[64 * HPITCH];   // 33792 B
    const int t = threadIdx.x;
    const int wave = t >> 6, l = t & 63, lane15 = l & 15, quad = l >> 4;
    const int r0 = blockIdx.x * 64;
    const int valid = min(64, BN - r0);

    // stage + convert: 64 rows x 16 float4 = 1024, 4/thread; also write xbf
    #pragma unroll
    for (int it = 0; it < 4; ++it) {
        int i = t + it * 256;          // 0..1023
        int m = i >> 4, c4 = i & 15;
        int row = min(r0 + m, BN - 1);
        float4 g = ((const float4*)x)[(size_t)row * 16 + c4];
        uint2 q = make_uint2(pack_bf(g.x, g.y), pack_bf(g.z, g.w));
        *(uint2*)(xs + m * XPITCH + c4 * 4) = q;
        *(uint2*)(xbf + (size_t)row * 64 + c4 * 4) = q;  // idempotent for clamped rows
    }
    __syncthreads();

    {   // GEMM1^T, K=64
        f32x4 acc[4][4];
        #pragma unroll
        for (int i = 0; i < 4; ++i)
            #pragma unroll
            for (int mt = 0; mt < 4; ++mt) acc[i][mt] = f32x4{0.f,0.f,0.f,0.f};
        const u16* w1 = frag + 32768;    // [16][2][64][8]
        #pragma unroll
        for (int kblk = 0; kblk < 2; ++kblk) {
            short8 bf[4], af[4];
            #pragma unroll
            for (int mt = 0; mt < 4; ++mt)
                bf[mt] = *(const short8*)(xs + (mt*16 + lane15) * XPITCH + kblk*32 + quad*8);
            #pragma unroll
            for (int i = 0; i < 4; ++i)
                af[i] = *(const short8*)(w1 + (((wave*4 + i)*2 + kblk)*64 + l) * 8);
            #pragma unroll
            for (int i = 0; i < 4; ++i)
                #pragma unroll
                for (int mt = 0; mt < 4; ++mt)
                    acc[i][mt] = __builtin_amdgcn_mfma_f32_16x16x32_bf16(af[i], bf[mt], acc[i][mt], 0, 0, 0);
        }
        #pragma unroll
        for (int i = 0; i < 4; ++i) {
            int n0 = (wave*4 + i)*16 + quad*4;
            float4 bv = *(const float4*)(nb1 + n0);
            #pragma unroll
            for (int mt = 0; mt < 4; ++mt) {
                int m = mt*16 + lane15;
                uint2 q = make_uint2(
                    pack_bf(fmaxf(acc[i][mt][0] + bv.x, 0.f), fmaxf(acc[i][mt][1] + bv.y, 0.f)),
                    pack_bf(fmaxf(acc[i][mt][2] + bv.z, 0.f), fmaxf(acc[i][mt][3] + bv.w, 0.f)));
                *(uint2*)(hid + m * HPITCH + n0) = q;
            }
        }
    }
    __syncthreads();

    {   // fused GEMM2^T: N=64, K=256 -> f32 out
        f32x4 acc[4];
        #pragma unroll
        for (int mt = 0; mt < 4; ++mt) acc[mt] = f32x4{0.f,0.f,0.f,0.f};
        const u16* w2 = frag + 65536;    // [4][8][64][8], ntile = wave
        #pragma unroll
        for (int kblk = 0; kblk < 8; ++kblk) {
            short8 bf[4], af;
            #pragma unroll
            for (int mt = 0; mt < 4; ++mt)
                bf[mt] = *(const short8*)(hid + (mt*16 + lane15) * HPITCH + kblk*32 + quad*8);
            af = *(const short8*)(w2 + ((wave*8 + kblk)*64 + l) * 8);
            #pragma unroll
            for (int mt = 0; mt < 4; ++mt)
                acc[mt] = __builtin_amdgcn_mfma_f32_16x16x32_bf16(af, bf[mt], acc[mt], 0, 0, 0);
        }
        int n0 = wave*16 + quad*4;
        float4 bv = *(const float4*)(bias2 + 64 + n0);
        #pragma unroll
        for (int mt = 0; mt < 4; ++mt) {
            int m = mt*16 + lane15;
            if (m < valid) {
                float4 o;
                o.x = acc[mt][0] + bv.x; o.y = acc[mt][1] + bv.y;
                o.z = acc[mt][2] + bv.z; o.w = acc[mt][3] + bv.w;
                *(float4*)(out + (size_t)(r0 + m) * 64 + n0) = o;
            }
        }
    }
}

// ---------------------------------------------------------------------------
// Edge MLP (dw-fused) -> perm rows: each edge's 64-col bf16 row written to
// both CSR slots pos[2e], pos[2e+1]. Full 128-B aligned line writes.
// ---------------------------------------------------------------------------
__global__ __launch_bounds__(256) void edge_emb_kernel(
    const u16* __restrict__ xbf, const int* __restrict__ edges,
    const float* __restrict__ eb1, const float* __restrict__ bias2,
    const u16* __restrict__ frag, const int* __restrict__ pos,
    u16* __restrict__ perm, int b)
{
    __shared__ u16 ein[64 * EPITCH];   // 17408 B; reused as erow after GEMM1
    __shared__ u16 hid[64 * HPITCH];   // 33792 B
    __shared__ int us[64], vs[64], ps[64], qs[64];
    const int t = threadIdx.x;
    const int wave = t >> 6, l = t & 63, lane15 = l & 15, quad = l >> 4;
    const int e0 = blockIdx.x * 64;
    const int valid = min(64, NE - e0);

    if (t < 64) {
        int e = min(e0 + t, NE - 1);
        us[t] = edges[2 * e];
        vs[t] = edges[2 * e + 1];
        ps[t] = pos[2 * e];
        qs[t] = pos[2 * e + 1];
    }
    __syncthreads();

    #pragma unroll
    for (int it = 0; it < 4; ++it) {
        int i = t + it * 256;           // 0..1023
        int m = i >> 4, c = i & 15;
        int half = c >> 3, c8 = c & 7;
        int node = half ? vs[m] : us[m];
        uint4 q = ((const uint4*)xbf)[(size_t)(b * NN + node) * 8 + c8];
        *(uint4*)(ein + m * EPITCH + half * 64 + c8 * 8) = q;
    }
    __syncthreads();

    {   // GEMM1^T, K=128
        f32x4 acc[4][4];
        #pragma unroll
        for (int i = 0; i < 4; ++i)
            #pragma unroll
            for (int mt = 0; mt < 4; ++mt) acc[i][mt] = f32x4{0.f,0.f,0.f,0.f};
        const u16* w1 = frag;            // [16][4][64][8]
        #pragma unroll
        for (int kblk = 0; kblk < 4; ++kblk) {
            short8 bf[4], af[4];
            #pragma unroll
            for (int mt = 0; mt < 4; ++mt)
                bf[mt] = *(const short8*)(ein + (mt*16 + lane15) * EPITCH + kblk*32 + quad*8);
            #pragma unroll
            for (int i = 0; i < 4; ++i)
                af[i] = *(const short8*)(w1 + (((wave*4 + i)*4 + kblk)*64 + l) * 8);
            #pragma unroll
            for (int i = 0; i < 4; ++i)
                #pragma unroll
                for (int mt = 0; mt < 4; ++mt)
                    acc[i][mt] = __builtin_amdgcn_mfma_f32_16x16x32_bf16(af[i], bf[mt], acc[i][mt], 0, 0, 0);
        }
        #pragma unroll
        for (int i = 0; i < 4; ++i) {
            int n0 = (wave*4 + i)*16 + quad*4;
            float4 bv = *(const float4*)(eb1 + n0);
            #pragma unroll
            for (int mt = 0; mt < 4; ++mt) {
                int m = mt*16 + lane15;
                uint2 q = make_uint2(
                    pack_bf(fmaxf(acc[i][mt][0] + bv.x, 0.f), fmaxf(acc[i][mt][1] + bv.y, 0.f)),
                    pack_bf(fmaxf(acc[i][mt][2] + bv.z, 0.f), fmaxf(acc[i][mt][3] + bv.w, 0.f)));
                *(uint2*)(hid + m * HPITCH + n0) = q;
            }
        }
    }
    __syncthreads();   // hid ready; ein reusable as erow

    {   // fused GEMM2^T: N=64, K=256 -> assemble rows in LDS
        f32x4 acc[4];
        #pragma unroll
        for (int mt = 0; mt < 4; ++mt) acc[mt] = f32x4{0.f,0.f,0.f,0.f};
        const u16* w2 = frag + 49152;    // [4][8][64][8], ntile = wave
        #pragma unroll
        for (int kblk = 0; kblk < 8; ++kblk) {
            short8 bf[4], af;
            #pragma unroll
            for (int mt = 0; mt < 4; ++mt)
                bf[mt] = *(const short8*)(hid + (mt*16 + lane15) * HPITCH + kblk*32 + quad*8);
            af = *(const short8*)(w2 + ((wave*8 + kblk)*64 + l) * 8);
            #pragma unroll
            for (int mt = 0; mt < 4; ++mt)
                acc[mt] = __builtin_amdgcn_mfma_f32_16x16x32_bf16(af, bf[mt], acc[mt], 0, 0, 0);
        }
        int n0 = wave*16 + quad*4;
        float4 bv = *(const float4*)(bias2 + n0);
        #pragma unroll
        for (int mt = 0; mt < 4; ++mt) {
            int m = mt*16 + lane15;
            uint2 q = make_uint2(
                pack_bf(acc[mt][0] + bv.x, acc[mt][1] + bv.y),
                pack_bf(acc[mt][2] + bv.z, acc[mt][3] + bv.w));
            *(uint2*)(ein + m * RPITCH + n0) = q;   // erow aliases ein
        }
    }
    __syncthreads();

    // store each row to both CSR slots: 64 edges x 2 dests x 8 uint4
    #pragma unroll
    for (int it = 0; it < 4; ++it) {
        int i = t + it * 256;          // 0..1023
        int dest = i >> 3, c8 = i & 7;
        int m = dest >> 1;
        if (m < valid) {
            int p = (dest & 1) ? qs[m] : ps[m];
            ((uint4*)(perm + (size_t)p * 64))[c8] = *(const uint4*)(ein + m * RPITCH + c8 * 8);
        }
    }
}

// ---------------------------------------------------------------------------
// Gather (streaming): out[b][n][:] += sum of perm rows off[n]..off[n+1]-1.
// One wave per node, 2x4 rows per iteration (ILP), fully coalesced.
// ---------------------------------------------------------------------------
__global__ __launch_bounds__(256) void gather_kernel(
    const u32* __restrict__ perm32, const int* __restrict__ off,
    float* __restrict__ out, int b)
{
    const int t = threadIdx.x, wave = t >> 6, l = t & 63;
    const int n = blockIdx.x * 4 + wave;
    const int base = off[n], cnt = off[n + 1] - base;
    if (cnt == 0) return;                   // wave-uniform
    const int slot = l >> 4, c8h = l & 15;  // row-in-group, 8B col
    float a0 = 0.f, a1 = 0.f, a2 = 0.f, a3 = 0.f;
    for (int j0 = 0; j0 < cnt; j0 += 8) {
        int jA = j0 + slot, jB = j0 + 4 + slot;
        const u32* rpA = perm32 + (size_t)(base + min(jA, cnt - 1)) * 32 + 2 * c8h;
        const u32* rpB = perm32 + (size_t)(base + min(jB, cnt - 1)) * 32 + 2 * c8h;
        u32 wA0 = rpA[0], wA1 = rpA[1];
        u32 wB0 = rpB[0], wB1 = rpB[1];
        union { u32 u; float f; } x0, x1, x2, x3;
        if (jA < cnt) {
            x0.u = wA0 << 16; x1.u = wA0 & 0xffff0000u;
            x2.u = wA1 << 16; x3.u = wA1 & 0xffff0000u;
            a0 += x0.f; a1 += x1.f; a2 += x2.f; a3 += x3.f;
        }
        if (jB < cnt) {
            x0.u = wB0 << 16; x1.u = wB0 & 0xffff0000u;
            x2.u = wB1 << 16; x3.u = wB1 & 0xffff0000u;
            a0 += x0.f; a1 += x1.f; a2 += x2.f; a3 += x3.f;
        }
    }
    a0 += __shfl_xor(a0, 16); a1 += __shfl_xor(a1, 16);
    a2 += __shfl_xor(a2, 16); a3 += __shfl_xor(a3, 16);
    a0 += __shfl_xor(a0, 32); a1 += __shfl_xor(a1, 32);
    a2 += __shfl_xor(a2, 32); a3 += __shfl_xor(a3, 32);
    if (l < 16) {
        float4* p = (float4*)(out + (size_t)(b * NN + n) * 64 + 4 * l);
        float4 h = *p;
        h.x += a0; h.y += a1; h.z += a2; h.w += a3;
        *p = h;
    }
}

// ---------------------------------------------------------------------------
extern "C" void kernel_launch(void* const* d_in, const int* in_sizes, int n_in,
                              void* d_out, int out_size, void* d_ws, size_t ws_size,
                              hipStream_t stream) {
    const float* x     = (const float*)d_in[0];
    const int*   edges = (const int*)d_in[1];
    const float* ew1   = (const float*)d_in[2];
    const float* eb1   = (const float*)d_in[3];
    const float* ew2   = (const float*)d_in[4];
    const float* eb2   = (const float*)d_in[5];
    const float* nw1   = (const float*)d_in[6];
    const float* nb1   = (const float*)d_in[7];
    const float* nw2   = (const float*)d_in[8];
    const float* nb2   = (const float*)d_in[9];
    const float* dw    = (const float*)d_in[10];
    const float* db    = (const float*)d_in[11];
    float* out = (float*)d_out;    // [BN][64]

    // Workspace layout (512B aligned); peak ~146 MB
    char* w = (char*)d_ws;
    size_t o = 0;
    auto take = [&](size_t bytes) { char* p = w + o; o = (o + bytes + 511) & ~(size_t)511; return p; };
    u16*   frag   = (u16*)  take(81920 * 2);               // 160 KB
    float* bias2  = (float*)take(128 * 4);
    int*   cursor = (int*)  take((size_t)NN * 4);          // 200 KB
    int*   off    = (int*)  take((size_t)(NN + 1) * 4);    // 200 KB
    int*   bsum   = (int*)  take((size_t)(NSB + 1) * 4);
    int*   boff   = (int*)  take((size_t)(NSB + 1) * 4);
    int*   pos    = (int*)  take((size_t)2 * NE * 4);      // 4 MB
    u16*   xbf    = (u16*)  take((size_t)BN * 64 * 2);     // 12.8 MB
    u16*   perm   = (u16*)  take((size_t)2 * NE * 64 * 2); // 128 MB (per-batch reuse)

    // CSR build (edges batch-invariant)
    csr_zero<<<NSB, 256, 0, stream>>>(cursor);
    csr_hist<<<(NE + 255) / 256, 256, 0, stream>>>(edges, cursor);
    scan_pass1<<<NSB, 256, 0, stream>>>(cursor, bsum);
    scan_pass2<<<1, 256, 0, stream>>>(bsum, boff);
    scan_pass3<<<NSB, 256, 0, stream>>>(cursor, boff, off);
    csr_fill<<<(NE + 255) / 256, 256, 0, stream>>>(edges, cursor, pos);

    // Weight prep
    swizzle_w1<<<192, 256, 0, stream>>>(ew1, nw1, frag);
    fuse_w2<<<128, 256, 0, stream>>>(ew2, nw2, dw, frag);
    fuse_bias<<<1, 128, 0, stream>>>(eb2, nb2, dw, db, bias2);

    // Node term -> out base (also produces xbf for the edge kernels)
    node_mlp_kernel<<<(BN + 63) / 64, 256, 0, stream>>>(x, nb1, bias2, frag, xbf, out);

    // Edge term per batch: MLP -> CSR-permuted rows -> streaming segmented sum
    for (int b = 0; b < BB; ++b) {
        edge_emb_kernel<<<(NE + 63) / 64, 256, 0, stream>>>(xbf, edges, eb1, bias2, frag, pos, perm, b);
        gather_kernel<<<NN / 4, 256, 0, stream>>>((const u32*)perm, off, out, b);
    }
}

// Round 11
// 445.320 us; speedup vs baseline: 7.6317x; 1.0170x over previous
//
#include <hip/hip_runtime.h>
#include <hip/hip_bf16.h>

// Problem constants
#define BB   2
#define NN   50000
#define BN   100000     // B*N
#define NE   500000
#define NSB  196        // scan blocks = ceil(NN/256)

using u16 = unsigned short;
using u32 = unsigned int;
typedef __attribute__((ext_vector_type(8))) short short8;   // 8 x bf16 (4 VGPRs)
typedef __attribute__((ext_vector_type(4))) float f32x4;    // MFMA accumulator

__device__ __forceinline__ u16 f2bf(float f) {   // RNE f32 -> bf16 (finite inputs)
    union { float f; u32 u; } w; w.f = f;
    return (u16)((w.u + 0x7fffu + ((w.u >> 16) & 1u)) >> 16);
}

#if defined(__has_builtin)
#if __has_builtin(__builtin_amdgcn_cvt_pk_bf16_f32)
#define HAVE_CVTPK 1
#endif
#endif

__device__ __forceinline__ u32 pack_bf(float lo, float hi) {
#ifdef HAVE_CVTPK
    auto r = __builtin_amdgcn_cvt_pk_bf16_f32(lo, hi);
    u32 out; __builtin_memcpy(&out, &r, sizeof(out));
    return out;
#else
    return ((u32)f2bf(hi) << 16) | (u32)f2bf(lo);
#endif
}

// ---------------------------------------------------------------------------
// CSR build: node -> contiguous slots [off[n], off[n+1]) ; pos[i] = slot of
// incidence i (i = 2e for u, 2e+1 for v).
// ---------------------------------------------------------------------------
__global__ __launch_bounds__(256) void csr_zero(int* __restrict__ cursor) {
    int i = blockIdx.x * 256 + threadIdx.x;
    if (i < NN) cursor[i] = 0;
}

__global__ __launch_bounds__(256) void csr_hist(const int* __restrict__ edges,
                                                int* __restrict__ cursor) {
    int e = blockIdx.x * 256 + threadIdx.x;
    if (e < NE) {
        atomicAdd(&cursor[edges[2*e]], 1);
        atomicAdd(&cursor[edges[2*e+1]], 1);
    }
}

__global__ __launch_bounds__(256) void scan_pass1(const int* __restrict__ cursor,
                                                  int* __restrict__ bsum) {
    __shared__ int s[256];
    const int t = threadIdx.x;
    int i = blockIdx.x * 256 + t;
    s[t] = (i < NN) ? cursor[i] : 0;
    __syncthreads();
    for (int d = 128; d > 0; d >>= 1) {
        if (t < d) s[t] += s[t + d];
        __syncthreads();
    }
    if (t == 0) bsum[blockIdx.x] = s[0];
}

__global__ __launch_bounds__(256) void scan_pass2(const int* __restrict__ bsum,
                                                  int* __restrict__ boff) {
    __shared__ int s[256];
    const int t = threadIdx.x;
    s[t] = (t < NSB) ? bsum[t] : 0;
    __syncthreads();
    for (int d = 1; d < 256; d <<= 1) {
        int v = (t >= d) ? s[t - d] : 0;
        __syncthreads();
        s[t] += v;
        __syncthreads();
    }
    if (t <= NSB) boff[t] = (t == 0) ? 0 : s[t - 1];
}

__global__ __launch_bounds__(256) void scan_pass3(int* __restrict__ cursor,
                                                  const int* __restrict__ boff,
                                                  int* __restrict__ off) {
    __shared__ int s[256];
    const int t = threadIdx.x;
    int i = blockIdx.x * 256 + t;
    int v = (i < NN) ? cursor[i] : 0;
    s[t] = v;
    __syncthreads();
    for (int d = 1; d < 256; d <<= 1) {
        int p = (t >= d) ? s[t - d] : 0;
        __syncthreads();
        s[t] += p;
        __syncthreads();
    }
    int excl = boff[blockIdx.x] + s[t] - v;
    if (i < NN) { off[i] = excl; cursor[i] = excl; }
    if (i == NN - 1) off[NN] = excl + v;
}

__global__ __launch_bounds__(256) void csr_fill(const int* __restrict__ edges,
                                                int* __restrict__ cursor,
                                                int* __restrict__ pos) {
    int e = blockIdx.x * 256 + threadIdx.x;
    if (e < NE) {
        pos[2*e]     = atomicAdd(&cursor[edges[2*e]], 1);
        pos[2*e + 1] = atomicAdd(&cursor[edges[2*e+1]], 1);
    }
}

// ---------------------------------------------------------------------------
// Unified weight prep: blocks 0..191 swizzle w1 (A-frag layout), 192..319
// compute fused W2' = W2@dw into A-frag, block 320 fuses biases.
// Regions (u16): w1e @0 ([16][4][64][8]), w1n @32768 ([16][2][64][8]),
//                w2e' @49152 ([4][8][64][8]), w2n' @65536 ([4][8][64][8]).
// ---------------------------------------------------------------------------
__global__ __launch_bounds__(256) void weight_prep(
    const float* __restrict__ ew1, const float* __restrict__ nw1,
    const float* __restrict__ ew2, const float* __restrict__ nw2,
    const float* __restrict__ dw,  const float* __restrict__ db,
    const float* __restrict__ eb2, const float* __restrict__ nb2,
    u16* __restrict__ frag, float* __restrict__ bias2)
{
    int blk = blockIdx.x, t = threadIdx.x;
    if (blk < 192) {
        int idx = blk * 256 + t;                 // 0..49151
        const float* src; int KB, local;
        if (idx < 32768) { local = idx;         src = ew1; KB = 4; }
        else             { local = idx - 32768; src = nw1; KB = 2; }
        int j = local & 7, l = (local >> 3) & 63, rest = local >> 9;
        int kblk = rest % KB, ntile = rest / KB;
        int n = ntile * 16 + (l & 15);
        int k = kblk * 32 + ((l >> 4) << 3) + j;
        frag[idx] = f2bf(src[k * 256 + n]);
    } else if (blk < 320) {
        int idx = (blk - 192) * 256 + t;         // 0..32767
        const float* src = (idx < 16384) ? ew2 : nw2;
        int local = idx & 16383;
        int j = local & 7, l = (local >> 3) & 63, rest = local >> 9;
        int kblk = rest & 7, ntile = rest >> 3;
        int n = ntile * 16 + (l & 15);
        int k = kblk * 32 + ((l >> 4) << 3) + j;
        float s = 0.f;
        for (int jj = 0; jj < 128; ++jj) s = fmaf(src[k * 128 + jj], dw[jj * 64 + n], s);
        frag[49152 + idx] = f2bf(s);
    } else if (t < 128) {
        int d = t & 63;
        const float* bsrc = (t >= 64) ? nb2 : eb2;
        float s = 0.f;
        #pragma unroll 4
        for (int j = 0; j < 128; ++j) s = fmaf(bsrc[j], dw[j * 64 + d], s);
        if (t >= 64) bias2[64 + d] = s + db[d];
        else         bias2[d] = s;
    }
}

// ---------------------------------------------------------------------------
// Node MLP (dw-fused) + x f32->bf16 conversion. Swizzled LDS (no padding):
// element (row, 16B-chunk c) lives at chunk c ^ (row & MASK).
// ---------------------------------------------------------------------------
__global__ __launch_bounds__(256) void node_mlp_kernel(
    const float* __restrict__ x, const float* __restrict__ nb1,
    const float* __restrict__ bias2, const u16* __restrict__ frag,
    u16* __restrict__ xbf, float* __restrict__ out)
{
    __shared__ u16 xs[64 * 64];     // 8 KB, 8 chunks/row, swizzle mask 7
    __shared__ u16 hid[64 * 256];   // 32 KB, 32 chunks/row, swizzle mask 15
    const int t = threadIdx.x;
    const int wave = t >> 6, l = t & 63, lane15 = l & 15, quad = l >> 4;
    const int r0 = blockIdx.x * 64;
    const int valid = min(64, BN - r0);

    // stage + convert: 64 rows x 16 float4, 4/thread; also write xbf
    #pragma unroll
    for (int it = 0; it < 4; ++it) {
        int i = t + it * 256;          // 0..1023
        int m = i >> 4, c4 = i & 15;   // row, float4-col (8B half-chunk)
        int row = min(r0 + m, BN - 1);
        float4 g = ((const float4*)x)[(size_t)row * 16 + c4];
        uint2 q = make_uint2(pack_bf(g.x, g.y), pack_bf(g.z, g.w));
        int chunk = c4 >> 1;
        *(uint2*)(xs + m * 64 + ((chunk ^ (m & 7)) << 3) + (c4 & 1) * 4) = q;
        *(uint2*)(xbf + (size_t)row * 64 + c4 * 4) = q;
    }
    __syncthreads();

    {   // GEMM1^T, K=64
        f32x4 acc[4][4];
        #pragma unroll
        for (int i = 0; i < 4; ++i)
            #pragma unroll
            for (int mt = 0; mt < 4; ++mt) acc[i][mt] = f32x4{0.f,0.f,0.f,0.f};
        const u16* w1 = frag + 32768;    // [16][2][64][8]
        #pragma unroll
        for (int kblk = 0; kblk < 2; ++kblk) {
            short8 bf[4], af[4];
            int chunk = kblk * 4 + quad;
            #pragma unroll
            for (int mt = 0; mt < 4; ++mt) {
                int row = mt*16 + lane15;
                bf[mt] = *(const short8*)(xs + row * 64 + ((chunk ^ (row & 7)) << 3));
            }
            #pragma unroll
            for (int i = 0; i < 4; ++i)
                af[i] = *(const short8*)(w1 + (((wave*4 + i)*2 + kblk)*64 + l) * 8);
            #pragma unroll
            for (int i = 0; i < 4; ++i)
                #pragma unroll
                for (int mt = 0; mt < 4; ++mt)
                    acc[i][mt] = __builtin_amdgcn_mfma_f32_16x16x32_bf16(af[i], bf[mt], acc[i][mt], 0, 0, 0);
        }
        #pragma unroll
        for (int i = 0; i < 4; ++i) {
            int n0 = (wave*4 + i)*16 + quad*4;
            int chunk = (wave*4 + i)*2 + (quad >> 1);
            float4 bv = *(const float4*)(nb1 + n0);
            #pragma unroll
            for (int mt = 0; mt < 4; ++mt) {
                int row = mt*16 + lane15;
                uint2 q = make_uint2(
                    pack_bf(fmaxf(acc[i][mt][0] + bv.x, 0.f), fmaxf(acc[i][mt][1] + bv.y, 0.f)),
                    pack_bf(fmaxf(acc[i][mt][2] + bv.z, 0.f), fmaxf(acc[i][mt][3] + bv.w, 0.f)));
                *(uint2*)(hid + row * 256 + ((chunk ^ (row & 15)) << 3) + (quad & 1) * 4) = q;
            }
        }
    }
    __syncthreads();

    {   // fused GEMM2^T: N=64, K=256 -> f32 out
        f32x4 acc[4];
        #pragma unroll
        for (int mt = 0; mt < 4; ++mt) acc[mt] = f32x4{0.f,0.f,0.f,0.f};
        const u16* w2 = frag + 65536;    // [4][8][64][8], ntile = wave
        #pragma unroll
        for (int kblk = 0; kblk < 8; ++kblk) {
            short8 bf[4], af;
            int chunk = kblk * 4 + quad;
            #pragma unroll
            for (int mt = 0; mt < 4; ++mt) {
                int row = mt*16 + lane15;
                bf[mt] = *(const short8*)(hid + row * 256 + ((chunk ^ (row & 15)) << 3));
            }
            af = *(const short8*)(w2 + ((wave*8 + kblk)*64 + l) * 8);
            #pragma unroll
            for (int mt = 0; mt < 4; ++mt)
                acc[mt] = __builtin_amdgcn_mfma_f32_16x16x32_bf16(af, bf[mt], acc[mt], 0, 0, 0);
        }
        int n0 = wave*16 + quad*4;
        float4 bv = *(const float4*)(bias2 + 64 + n0);
        #pragma unroll
        for (int mt = 0; mt < 4; ++mt) {
            int m = mt*16 + lane15;
            if (m < valid) {
                float4 o;
                o.x = acc[mt][0] + bv.x; o.y = acc[mt][1] + bv.y;
                o.z = acc[mt][2] + bv.z; o.w = acc[mt][3] + bv.w;
                *(float4*)(out + (size_t)(r0 + m) * 64 + n0) = o;
            }
        }
    }
}

// ---------------------------------------------------------------------------
// Edge MLP (dw-fused) -> perm rows (both CSR slots). Swizzled LDS.
// b = b_base + blockIdx.y ; perm buffer offset pstride16 * blockIdx.y.
// ---------------------------------------------------------------------------
__global__ __launch_bounds__(256) void edge_emb_kernel(
    const u16* __restrict__ xbf, const int* __restrict__ edges,
    const float* __restrict__ eb1, const float* __restrict__ bias2,
    const u16* __restrict__ frag, const int* __restrict__ pos,
    u16* __restrict__ perm, int b_base, size_t pstride16)
{
    __shared__ u16 ein[64 * 128];   // 16 KB, 16 chunks/row, mask 15; reused as erow
    __shared__ u16 hid[64 * 256];   // 32 KB, 32 chunks/row, mask 15
    __shared__ int us[64], vs[64], ps[64], qs[64];
    const int t = threadIdx.x;
    const int wave = t >> 6, l = t & 63, lane15 = l & 15, quad = l >> 4;
    const int b = b_base + blockIdx.y;
    u16* permb = perm + pstride16 * blockIdx.y;
    const int e0 = blockIdx.x * 64;
    const int valid = min(64, NE - e0);

    if (t < 64) {
        int e = min(e0 + t, NE - 1);
        us[t] = edges[2 * e];
        vs[t] = edges[2 * e + 1];
        ps[t] = pos[2 * e];
        qs[t] = pos[2 * e + 1];
    }
    __syncthreads();

    // gather bf16 rows: 64 edges x 16 chunks (8 from x[u], 8 from x[v])
    #pragma unroll
    for (int it = 0; it < 4; ++it) {
        int i = t + it * 256;           // 0..1023
        int m = i >> 4, c = i & 15;     // row, chunk
        int half = c >> 3, c8 = c & 7;
        int node = half ? vs[m] : us[m];
        uint4 q = ((const uint4*)xbf)[(size_t)(b * NN + node) * 8 + c8];
        *(uint4*)(ein + m * 128 + ((c ^ (m & 15)) << 3)) = q;
    }
    __syncthreads();

    {   // GEMM1^T, K=128
        f32x4 acc[4][4];
        #pragma unroll
        for (int i = 0; i < 4; ++i)
            #pragma unroll
            for (int mt = 0; mt < 4; ++mt) acc[i][mt] = f32x4{0.f,0.f,0.f,0.f};
        const u16* w1 = frag;            // [16][4][64][8]
        #pragma unroll
        for (int kblk = 0; kblk < 4; ++kblk) {
            short8 bf[4], af[4];
            int chunk = kblk * 4 + quad;
            #pragma unroll
            for (int mt = 0; mt < 4; ++mt) {
                int row = mt*16 + lane15;
                bf[mt] = *(const short8*)(ein + row * 128 + ((chunk ^ (row & 15)) << 3));
            }
            #pragma unroll
            for (int i = 0; i < 4; ++i)
                af[i] = *(const short8*)(w1 + (((wave*4 + i)*4 + kblk)*64 + l) * 8);
            #pragma unroll
            for (int i = 0; i < 4; ++i)
                #pragma unroll
                for (int mt = 0; mt < 4; ++mt)
                    acc[i][mt] = __builtin_amdgcn_mfma_f32_16x16x32_bf16(af[i], bf[mt], acc[i][mt], 0, 0, 0);
        }
        #pragma unroll
        for (int i = 0; i < 4; ++i) {
            int n0 = (wave*4 + i)*16 + quad*4;
            int chunk = (wave*4 + i)*2 + (quad >> 1);
            float4 bv = *(const float4*)(eb1 + n0);
            #pragma unroll
            for (int mt = 0; mt < 4; ++mt) {
                int row = mt*16 + lane15;
                uint2 q = make_uint2(
                    pack_bf(fmaxf(acc[i][mt][0] + bv.x, 0.f), fmaxf(acc[i][mt][1] + bv.y, 0.f)),
                    pack_bf(fmaxf(acc[i][mt][2] + bv.z, 0.f), fmaxf(acc[i][mt][3] + bv.w, 0.f)));
                *(uint2*)(hid + row * 256 + ((chunk ^ (row & 15)) << 3) + (quad & 1) * 4) = q;
            }
        }
    }
    __syncthreads();   // hid ready; ein reusable as erow (64 x 64 u16, mask 7)

    {   // fused GEMM2^T: N=64, K=256 -> assemble rows in LDS
        f32x4 acc[4];
        #pragma unroll
        for (int mt = 0; mt < 4; ++mt) acc[mt] = f32x4{0.f,0.f,0.f,0.f};
        const u16* w2 = frag + 49152;    // [4][8][64][8], ntile = wave
        #pragma unroll
        for (int kblk = 0; kblk < 8; ++kblk) {
            short8 bf[4], af;
            int chunk = kblk * 4 + quad;
            #pragma unroll
            for (int mt = 0; mt < 4; ++mt) {
                int row = mt*16 + lane15;
                bf[mt] = *(const short8*)(hid + row * 256 + ((chunk ^ (row & 15)) << 3));
            }
            af = *(const short8*)(w2 + ((wave*8 + kblk)*64 + l) * 8);
            #pragma unroll
            for (int mt = 0; mt < 4; ++mt)
                acc[mt] = __builtin_amdgcn_mfma_f32_16x16x32_bf16(af, bf[mt], acc[mt], 0, 0, 0);
        }
        int n0 = wave*16 + quad*4;
        int chunk = wave*2 + (quad >> 1);
        float4 bv = *(const float4*)(bias2 + n0);
        #pragma unroll
        for (int mt = 0; mt < 4; ++mt) {
            int m = mt*16 + lane15;
            uint2 q = make_uint2(
                pack_bf(acc[mt][0] + bv.x, acc[mt][1] + bv.y),
                pack_bf(acc[mt][2] + bv.z, acc[mt][3] + bv.w));
            *(uint2*)(ein + m * 64 + ((chunk ^ (m & 7)) << 3) + (quad & 1) * 4) = q;
        }
    }
    __syncthreads();

    // store each row to both CSR slots: 64 edges x 2 dests x 8 uint4
    #pragma unroll
    for (int it = 0; it < 4; ++it) {
        int i = t + it * 256;          // 0..1023
        int dest = i >> 3, c8 = i & 7;
        int m = dest >> 1;
        if (m < valid) {
            int p = (dest & 1) ? qs[m] : ps[m];
            ((uint4*)(permb + (size_t)p * 64))[c8] =
                *(const uint4*)(ein + m * 64 + ((c8 ^ (m & 7)) << 3));
        }
    }
}

// ---------------------------------------------------------------------------
// Gather (streaming): out[b][n][:] += sum of perm rows off[n]..off[n+1]-1.
// One wave per node, 2x4 rows per iteration, fully coalesced.
// ---------------------------------------------------------------------------
__global__ __launch_bounds__(256) void gather_kernel(
    const u32* __restrict__ perm32, const int* __restrict__ off,
    float* __restrict__ out, int b_base, size_t pstride16)
{
    const int t = threadIdx.x, wave = t >> 6, l = t & 63;
    const int b = b_base + blockIdx.y;
    const u32* permb = perm32 + (pstride16 >> 1) * blockIdx.y;
    const int n = blockIdx.x * 4 + wave;
    const int base = off[n], cnt = off[n + 1] - base;
    if (cnt == 0) return;                   // wave-uniform
    const int slot = l >> 4, c8h = l & 15;  // row-in-group, 8B col
    float a0 = 0.f, a1 = 0.f, a2 = 0.f, a3 = 0.f;
    for (int j0 = 0; j0 < cnt; j0 += 8) {
        int jA = j0 + slot, jB = j0 + 4 + slot;
        const u32* rpA = permb + (size_t)(base + min(jA, cnt - 1)) * 32 + 2 * c8h;
        const u32* rpB = permb + (size_t)(base + min(jB, cnt - 1)) * 32 + 2 * c8h;
        u32 wA0 = rpA[0], wA1 = rpA[1];
        u32 wB0 = rpB[0], wB1 = rpB[1];
        union { u32 u; float f; } x0, x1, x2, x3;
        if (jA < cnt) {
            x0.u = wA0 << 16; x1.u = wA0 & 0xffff0000u;
            x2.u = wA1 << 16; x3.u = wA1 & 0xffff0000u;
            a0 += x0.f; a1 += x1.f; a2 += x2.f; a3 += x3.f;
        }
        if (jB < cnt) {
            x0.u = wB0 << 16; x1.u = wB0 & 0xffff0000u;
            x2.u = wB1 << 16; x3.u = wB1 & 0xffff0000u;
            a0 += x0.f; a1 += x1.f; a2 += x2.f; a3 += x3.f;
        }
    }
    a0 += __shfl_xor(a0, 16); a1 += __shfl_xor(a1, 16);
    a2 += __shfl_xor(a2, 16); a3 += __shfl_xor(a3, 16);
    a0 += __shfl_xor(a0, 32); a1 += __shfl_xor(a1, 32);
    a2 += __shfl_xor(a2, 32); a3 += __shfl_xor(a3, 32);
    if (l < 16) {
        float4* p = (float4*)(out + (size_t)(b * NN + n) * 64 + 4 * l);
        float4 h = *p;
        h.x += a0; h.y += a1; h.z += a2; h.w += a3;
        *p = h;
    }
}

// ---------------------------------------------------------------------------
extern "C" void kernel_launch(void* const* d_in, const int* in_sizes, int n_in,
                              void* d_out, int out_size, void* d_ws, size_t ws_size,
                              hipStream_t stream) {
    const float* x     = (const float*)d_in[0];
    const int*   edges = (const int*)d_in[1];
    const float* ew1   = (const float*)d_in[2];
    const float* eb1   = (const float*)d_in[3];
    const float* ew2   = (const float*)d_in[4];
    const float* eb2   = (const float*)d_in[5];
    const float* nw1   = (const float*)d_in[6];
    const float* nb1   = (const float*)d_in[7];
    const float* nw2   = (const float*)d_in[8];
    const float* nb2   = (const float*)d_in[9];
    const float* dw    = (const float*)d_in[10];
    const float* db    = (const float*)d_in[11];
    float* out = (float*)d_out;    // [BN][64]

    // Workspace layout (512B aligned)
    char* w = (char*)d_ws;
    size_t o = 0;
    auto take = [&](size_t bytes) { char* p = w + o; o = (o + bytes + 511) & ~(size_t)511; return p; };
    u16*   frag   = (u16*)  take(81920 * 2);               // 160 KB
    float* bias2  = (float*)take(128 * 4);
    int*   cursor = (int*)  take((size_t)NN * 4);          // 200 KB
    int*   off    = (int*)  take((size_t)(NN + 1) * 4);    // 200 KB
    int*   bsum   = (int*)  take((size_t)(NSB + 1) * 4);
    int*   boff   = (int*)  take((size_t)(NSB + 1) * 4);
    int*   pos    = (int*)  take((size_t)2 * NE * 4);      // 4 MB
    u16*   xbf    = (u16*)  take((size_t)BN * 64 * 2);     // 12.8 MB
    const size_t permElems = (size_t)2 * NE * 64;          // u16 elems per batch
    u16*   perm   = (u16*)  take(permElems * 2);           // 128 MB
    // If ws permits a second perm buffer, both batches run in one dispatch.
    bool dual = (o + permElems * 2) <= ws_size;
    if (dual) take(permElems * 2);

    // CSR build (edges batch-invariant)
    csr_zero<<<NSB, 256, 0, stream>>>(cursor);
    csr_hist<<<(NE + 255) / 256, 256, 0, stream>>>(edges, cursor);
    scan_pass1<<<NSB, 256, 0, stream>>>(cursor, bsum);
    scan_pass2<<<1, 256, 0, stream>>>(bsum, boff);
    scan_pass3<<<NSB, 256, 0, stream>>>(cursor, boff, off);
    csr_fill<<<(NE + 255) / 256, 256, 0, stream>>>(edges, cursor, pos);

    // Weight prep (one dispatch)
    weight_prep<<<321, 256, 0, stream>>>(ew1, nw1, ew2, nw2, dw, db, eb2, nb2, frag, bias2);

    // Node term -> out base (also produces xbf for the edge kernels)
    node_mlp_kernel<<<(BN + 63) / 64, 256, 0, stream>>>(x, nb1, bias2, frag, xbf, out);

    // Edge term: MLP -> CSR-permuted rows -> streaming segmented sum
    if (dual) {
        edge_emb_kernel<<<dim3((NE + 63) / 64, BB), 256, 0, stream>>>(
            xbf, edges, eb1, bias2, frag, pos, perm, 0, permElems);
        gather_kernel<<<dim3(NN / 4, BB), 256, 0, stream>>>(
            (const u32*)perm, off, out, 0, permElems);
    } else {
        for (int b = 0; b < BB; ++b) {
            edge_emb_kernel<<<dim3((NE + 63) / 64, 1), 256, 0, stream>>>(
                xbf, edges, eb1, bias2, frag, pos, perm, b, 0);
            gather_kernel<<<dim3(NN / 4, 1), 256, 0, stream>>>(
                (const u32*)perm, off, out, b, 0);
        }
    }
}